// Round 1
// baseline (4511.067 us; speedup 1.0000x reference)
//
#include <hip/hip_runtime.h>

#define BB 4
#define NN 1024
#define DD 512
#define HH 8
#define DHH 64
#define FFF 2048

__device__ inline float wave_sum(float v) {
#pragma unroll
  for (int off = 32; off; off >>= 1) v += __shfl_xor(v, off);
  return v;
}

// ---------------- PE add + dual LayerNorm (q,k share mean/var) ----------------
__global__ __launch_bounds__(512) void pe_ln_kernel(
    const float* __restrict__ x, const float* __restrict__ coords,
    const float* __restrict__ W_pe, const float* __restrict__ b_pe,
    const float* __restrict__ g_q, const float* __restrict__ bt_q,
    const float* __restrict__ g_k, const float* __restrict__ bt_k,
    float* __restrict__ q_ln, float* __restrict__ k_ln) {
  int row = blockIdx.x;            // b*N + n
  int tid = threadIdx.x;           // 512
  float c0 = coords[(size_t)row * 2 + 0];
  float c1 = coords[(size_t)row * 2 + 1];
  size_t idx = (size_t)row * DD + tid;
  float val = x[idx] + c0 * W_pe[tid] + c1 * W_pe[DD + tid] + b_pe[tid];

  __shared__ float ws[8], ws2[8];
  float s = wave_sum(val);
  if ((tid & 63) == 0) ws[tid >> 6] = s;
  __syncthreads();
  float mean = 0.f;
#pragma unroll
  for (int w = 0; w < 8; ++w) mean += ws[w];
  mean *= (1.f / DD);
  float dv = val - mean;
  float s2 = wave_sum(dv * dv);
  if ((tid & 63) == 0) ws2[tid >> 6] = s2;
  __syncthreads();
  float var = 0.f;
#pragma unroll
  for (int w = 0; w < 8; ++w) var += ws2[w];
  var *= (1.f / DD);
  float rstd = rsqrtf(var + 1e-5f);
  q_ln[idx] = dv * rstd * g_q[tid] + bt_q[tid];
  k_ln[idx] = dv * rstd * g_k[tid] + bt_k[tid];
}

// ---------------- residual add + LayerNorm ----------------
__global__ __launch_bounds__(512) void add_ln_kernel(
    const float* __restrict__ a, const float* __restrict__ r,
    const float* __restrict__ g, const float* __restrict__ bt,
    float* __restrict__ out) {
  int row = blockIdx.x;
  int tid = threadIdx.x;
  size_t idx = (size_t)row * DD + tid;
  float val = a[idx] + r[idx];
  __shared__ float ws[8], ws2[8];
  float s = wave_sum(val);
  if ((tid & 63) == 0) ws[tid >> 6] = s;
  __syncthreads();
  float mean = 0.f;
#pragma unroll
  for (int w = 0; w < 8; ++w) mean += ws[w];
  mean *= (1.f / DD);
  float dv = val - mean;
  float s2 = wave_sum(dv * dv);
  if ((tid & 63) == 0) ws2[tid >> 6] = s2;
  __syncthreads();
  float var = 0.f;
#pragma unroll
  for (int w = 0; w < 8; ++w) var += ws2[w];
  var *= (1.f / DD);
  float rstd = rsqrtf(var + 1e-5f);
  out[idx] = dv * rstd * g[tid] + bt[tid];
}

// ---------------- tiled f32 GEMM: C = act(A[M,K] @ W[K,Nc] + bias) ----------------
template <int ACT>
__global__ __launch_bounds__(256) void gemm_kernel(
    const float* __restrict__ A, const float* __restrict__ W,
    const float* __restrict__ bias, float* __restrict__ C,
    int M, int Nc, int K) {
  __shared__ float As[16][65];
  __shared__ float Bs[16][65];
  int bm = blockIdx.y * 64, bn = blockIdx.x * 64;
  int tid = threadIdx.x;
  int tr = (tid >> 4) << 2;
  int tc = (tid & 15) << 2;
  float acc[4][4] = {};
  for (int k0 = 0; k0 < K; k0 += 16) {
#pragma unroll
    for (int i = 0; i < 4; ++i) {
      int e = tid + i * 256;
      int m = e >> 4, kk = e & 15;
      As[kk][m] = A[(size_t)(bm + m) * K + k0 + kk];
    }
#pragma unroll
    for (int i = 0; i < 4; ++i) {
      int e = tid + i * 256;
      int kk = e >> 6, n = e & 63;
      Bs[kk][n] = W[(size_t)(k0 + kk) * Nc + bn + n];
    }
    __syncthreads();
#pragma unroll
    for (int kk = 0; kk < 16; ++kk) {
      float a[4], bv[4];
#pragma unroll
      for (int u = 0; u < 4; ++u) a[u] = As[kk][tr + u];
#pragma unroll
      for (int v = 0; v < 4; ++v) bv[v] = Bs[kk][tc + v];
#pragma unroll
      for (int u = 0; u < 4; ++u)
#pragma unroll
        for (int v = 0; v < 4; ++v) acc[u][v] = fmaf(a[u], bv[v], acc[u][v]);
    }
    __syncthreads();
  }
#pragma unroll
  for (int u = 0; u < 4; ++u) {
#pragma unroll
    for (int v = 0; v < 4; ++v) {
      float val = acc[u][v];
      if (bias) val += bias[bn + tc + v];
      if (ACT == 1) val = val > 0.f ? val : 0.2f * val;
      C[(size_t)(bm + tr + u) * Nc + bn + tc + v] = val;
    }
  }
}

// ---------------- per-head L2 normalize (+ optional logit scale) ----------------
__global__ __launch_bounds__(512) void headnorm_kernel(
    float* __restrict__ data, const float* __restrict__ logit_scale) {
  int row = blockIdx.x;
  int tid = threadIdx.x;  // wave (64 lanes) == one head (DH=64)
  size_t idx = (size_t)row * DD + tid;
  float v = data[idx];
  float ss = wave_sum(v * v);
  float nrm = fmaxf(sqrtf(ss), 1e-12f);
  float scale = 1.0f;
  if (logit_scale) {
    float ls = logit_scale[tid >> 6];
    scale = __expf(fminf(ls, 4.605170185988091f));  // ln(100)
  }
  data[idx] = v / nrm * scale;
}

// ---------------- attention: one block per (b,h,q-row), bias MLP fused ----------------
__global__ __launch_bounds__(256) void attn_kernel(
    const float* __restrict__ qn,   // [B,N,H,DH], logit scale folded in
    const float* __restrict__ kn,   // [B,N,H,DH]
    const float* __restrict__ vp,   // [B,N,H,DH]
    const float* __restrict__ coords,
    const float* __restrict__ W_r1, const float* __restrict__ b_r1,
    const float* __restrict__ W_r2, const float* __restrict__ b_r2,
    float* __restrict__ att) {      // [B,N,H,DH] == [B,N,D]
  int i = blockIdx.x, h = blockIdx.y, b = blockIdx.z;
  int tid = threadIdx.x;

  __shared__ float qrow[DHH];
  __shared__ float s[NN];
  __shared__ float wr1[32], br1[16], wr2[16];
  __shared__ float smax[4], ssum[4];
  __shared__ float pv[4][DHH];

  if (tid < DHH) qrow[tid] = qn[((size_t)(b * NN + i) * HH + h) * DHH + tid];
  if (tid < 32) wr1[tid] = W_r1[tid];            // [2,16] row-major
  if (tid < 16) { br1[tid] = b_r1[tid]; wr2[tid] = W_r2[tid * HH + h]; }
  __syncthreads();

  float ci0 = coords[(size_t)(b * NN + i) * 2 + 0];
  float ci1 = coords[(size_t)(b * NN + i) * 2 + 1];
  float br2h = b_r2[h];

  float lmax = -1e30f;
  for (int j = tid; j < NN; j += 256) {
    const float* krow = &kn[((size_t)(b * NN + j) * HH + h) * DHH];
    float dot = 0.f;
#pragma unroll
    for (int d = 0; d < DHH; ++d) dot = fmaf(qrow[d], krow[d], dot);
    float r0 = ci0 - coords[(size_t)(b * NN + j) * 2 + 0];
    float r1 = ci1 - coords[(size_t)(b * NN + j) * 2 + 1];
    float bias = br2h;
#pragma unroll
    for (int l = 0; l < 16; ++l) {
      float hv = fmaf(r0, wr1[l], fmaf(r1, wr1[16 + l], br1[l]));
      hv = fmaxf(hv, 0.f);
      bias = fmaf(hv, wr2[l], bias);
    }
    float sv = dot + bias;
    s[j] = sv;
    lmax = fmaxf(lmax, sv);
  }
#pragma unroll
  for (int off = 32; off; off >>= 1) lmax = fmaxf(lmax, __shfl_xor(lmax, off));
  if ((tid & 63) == 0) smax[tid >> 6] = lmax;
  __syncthreads();
  float gmax = fmaxf(fmaxf(smax[0], smax[1]), fmaxf(smax[2], smax[3]));

  float lsum = 0.f;
  for (int j = tid; j < NN; j += 256) {
    float p = __expf(s[j] - gmax);
    s[j] = p;
    lsum += p;
  }
  lsum = wave_sum(lsum);
  if ((tid & 63) == 0) ssum[tid >> 6] = lsum;
  __syncthreads();   // also orders s[] writes before PV reads
  float gsum = ssum[0] + ssum[1] + ssum[2] + ssum[3];

  int d = tid & 63, part = tid >> 6;
  float acc = 0.f;
  for (int j = part; j < NN; j += 4)
    acc = fmaf(s[j], vp[((size_t)(b * NN + j) * HH + h) * DHH + d], acc);
  pv[part][d] = acc;
  __syncthreads();
  if (tid < DHH) {
    float o = (pv[0][tid] + pv[1][tid] + pv[2][tid] + pv[3][tid]) / gsum;
    att[((size_t)(b * NN + i) * HH + h) * DHH + tid] = o;
  }
}

// ---------------- launcher ----------------
extern "C" void kernel_launch(void* const* d_in, const int* in_sizes, int n_in,
                              void* d_out, int out_size, void* d_ws, size_t ws_size,
                              hipStream_t stream) {
  const float* x      = (const float*)d_in[0];
  const float* coords = (const float*)d_in[1];
  const float* Wq = (const float*)d_in[2];  const float* bq = (const float*)d_in[3];
  const float* Wk = (const float*)d_in[4];  const float* bk = (const float*)d_in[5];
  const float* Wv = (const float*)d_in[6];  const float* bv = (const float*)d_in[7];
  const float* Wo = (const float*)d_in[8];  const float* bo = (const float*)d_in[9];
  const float* logit_scale = (const float*)d_in[10];
  const float* W_pe = (const float*)d_in[11]; const float* b_pe = (const float*)d_in[12];
  const float* W_r1 = (const float*)d_in[13]; const float* b_r1 = (const float*)d_in[14];
  const float* W_r2 = (const float*)d_in[15]; const float* b_r2 = (const float*)d_in[16];
  const float* g_peq = (const float*)d_in[17]; const float* bt_peq = (const float*)d_in[18];
  const float* g_pek = (const float*)d_in[19]; const float* bt_pek = (const float*)d_in[20];
  const float* g2 = (const float*)d_in[21]; const float* bt2 = (const float*)d_in[22];
  const float* g3 = (const float*)d_in[23]; const float* bt3 = (const float*)d_in[24];
  const float* W_ff1 = (const float*)d_in[25];
  const float* W_ff2 = (const float*)d_in[26];
  float* out = (float*)d_out;

  const size_t T = (size_t)BB * NN;      // 4096 rows
  const size_t SL = T * DD;              // 2M floats per [B,N,D] slab
  float* ws = (float*)d_ws;
  // aliased layout (all deterministic write-before-read):
  float* q_ln = ws + 0 * SL;
  float* k_ln = ws + 1 * SL;
  float* qp   = ws + 2 * SL;
  float* kp   = ws + 3 * SL;
  float* vp   = ws + 4 * SL;
  float* att  = ws + 5 * SL;
  float* proj = ws + 0 * SL;             // reuse q_ln (dead)
  float* x1   = ws + 1 * SL;             // reuse k_ln (dead)
  float* hid  = ws + 2 * SL;             // 8M floats, spans qp..att (dead)
  float* mlp  = ws + 6 * SL;

  pe_ln_kernel<<<dim3(T), dim3(512), 0, stream>>>(
      x, coords, W_pe, b_pe, g_peq, bt_peq, g_pek, bt_pek, q_ln, k_ln);

  gemm_kernel<0><<<dim3(DD / 64, T / 64), dim3(256), 0, stream>>>(
      q_ln, Wq, bq, qp, (int)T, DD, DD);
  gemm_kernel<0><<<dim3(DD / 64, T / 64), dim3(256), 0, stream>>>(
      k_ln, Wk, bk, kp, (int)T, DD, DD);
  gemm_kernel<0><<<dim3(DD / 64, T / 64), dim3(256), 0, stream>>>(
      x, Wv, bv, vp, (int)T, DD, DD);

  headnorm_kernel<<<dim3(T), dim3(512), 0, stream>>>(qp, logit_scale);
  headnorm_kernel<<<dim3(T), dim3(512), 0, stream>>>(kp, nullptr);

  attn_kernel<<<dim3(NN, HH, BB), dim3(256), 0, stream>>>(
      qp, kp, vp, coords, W_r1, b_r1, W_r2, b_r2, att);

  gemm_kernel<0><<<dim3(DD / 64, T / 64), dim3(256), 0, stream>>>(
      att, Wo, bo, proj, (int)T, DD, DD);

  add_ln_kernel<<<dim3(T), dim3(512), 0, stream>>>(x, proj, g2, bt2, x1);

  gemm_kernel<1><<<dim3(FFF / 64, T / 64), dim3(256), 0, stream>>>(
      x1, W_ff1, nullptr, hid, (int)T, FFF, DD);
  gemm_kernel<1><<<dim3(DD / 64, T / 64), dim3(256), 0, stream>>>(
      hid, W_ff2, nullptr, mlp, (int)T, DD, FFF);

  add_ln_kernel<<<dim3(T), dim3(512), 0, stream>>>(x1, mlp, g3, bt3, out);
}

// Round 2
// 713.590 us; speedup vs baseline: 6.3216x; 6.3216x over previous
//
#include <hip/hip_runtime.h>

#define BB 4
#define NN 1024
#define DD 512
#define HH 8
#define DHH 64
#define FFF 2048

typedef __attribute__((ext_vector_type(8))) short bf16x8;
typedef __attribute__((ext_vector_type(4))) float f32x4;

__device__ inline float wave_sum(float v) {
#pragma unroll
  for (int off = 32; off; off >>= 1) v += __shfl_xor(v, off);
  return v;
}

__device__ inline unsigned short cvt_bf16(float f) {
  union { float f; unsigned u; } x;
  x.f = f;
  unsigned r = x.u + 0x7FFFu + ((x.u >> 16) & 1u);
  return (unsigned short)(r >> 16);
}

// ---------------- PE add + dual LayerNorm (q,k share mean/var) ----------------
__global__ __launch_bounds__(512) void pe_ln_kernel(
    const float* __restrict__ x, const float* __restrict__ coords,
    const float* __restrict__ W_pe, const float* __restrict__ b_pe,
    const float* __restrict__ g_q, const float* __restrict__ bt_q,
    const float* __restrict__ g_k, const float* __restrict__ bt_k,
    float* __restrict__ q_ln, float* __restrict__ k_ln) {
  int row = blockIdx.x;
  int tid = threadIdx.x;
  float c0 = coords[(size_t)row * 2 + 0];
  float c1 = coords[(size_t)row * 2 + 1];
  size_t idx = (size_t)row * DD + tid;
  float val = x[idx] + c0 * W_pe[tid] + c1 * W_pe[DD + tid] + b_pe[tid];

  __shared__ float ws[8], ws2[8];
  float s = wave_sum(val);
  if ((tid & 63) == 0) ws[tid >> 6] = s;
  __syncthreads();
  float mean = 0.f;
#pragma unroll
  for (int w = 0; w < 8; ++w) mean += ws[w];
  mean *= (1.f / DD);
  float dv = val - mean;
  float s2 = wave_sum(dv * dv);
  if ((tid & 63) == 0) ws2[tid >> 6] = s2;
  __syncthreads();
  float var = 0.f;
#pragma unroll
  for (int w = 0; w < 8; ++w) var += ws2[w];
  var *= (1.f / DD);
  float rstd = rsqrtf(var + 1e-5f);
  q_ln[idx] = dv * rstd * g_q[tid] + bt_q[tid];
  k_ln[idx] = dv * rstd * g_k[tid] + bt_k[tid];
}

// ---------------- residual add + LayerNorm ----------------
__global__ __launch_bounds__(512) void add_ln_kernel(
    const float* __restrict__ a, const float* __restrict__ r,
    const float* __restrict__ g, const float* __restrict__ bt,
    float* __restrict__ out) {
  int row = blockIdx.x;
  int tid = threadIdx.x;
  size_t idx = (size_t)row * DD + tid;
  float val = a[idx] + r[idx];
  __shared__ float ws[8], ws2[8];
  float s = wave_sum(val);
  if ((tid & 63) == 0) ws[tid >> 6] = s;
  __syncthreads();
  float mean = 0.f;
#pragma unroll
  for (int w = 0; w < 8; ++w) mean += ws[w];
  mean *= (1.f / DD);
  float dv = val - mean;
  float s2 = wave_sum(dv * dv);
  if ((tid & 63) == 0) ws2[tid >> 6] = s2;
  __syncthreads();
  float var = 0.f;
#pragma unroll
  for (int w = 0; w < 8; ++w) var += ws2[w];
  var *= (1.f / DD);
  float rstd = rsqrtf(var + 1e-5f);
  out[idx] = dv * rstd * g[tid] + bt[tid];
}

// ---------------- tiled f32 GEMM: C = act(A[M,K] @ W[K,Nc] + bias) ----------------
template <int ACT>
__global__ __launch_bounds__(256) void gemm_kernel(
    const float* __restrict__ A, const float* __restrict__ W,
    const float* __restrict__ bias, float* __restrict__ C,
    int M, int Nc, int K) {
  __shared__ float As[16][65];
  __shared__ float Bs[16][65];
  int bm = blockIdx.y * 64, bn = blockIdx.x * 64;
  int tid = threadIdx.x;
  int tr = (tid >> 4) << 2;
  int tc = (tid & 15) << 2;
  float acc[4][4] = {};
  for (int k0 = 0; k0 < K; k0 += 16) {
#pragma unroll
    for (int i = 0; i < 4; ++i) {
      int e = tid + i * 256;
      int m = e >> 4, kk = e & 15;
      As[kk][m] = A[(size_t)(bm + m) * K + k0 + kk];
    }
#pragma unroll
    for (int i = 0; i < 4; ++i) {
      int e = tid + i * 256;
      int kk = e >> 6, n = e & 63;
      Bs[kk][n] = W[(size_t)(k0 + kk) * Nc + bn + n];
    }
    __syncthreads();
#pragma unroll
    for (int kk = 0; kk < 16; ++kk) {
      float a[4], bv[4];
#pragma unroll
      for (int u = 0; u < 4; ++u) a[u] = As[kk][tr + u];
#pragma unroll
      for (int v = 0; v < 4; ++v) bv[v] = Bs[kk][tc + v];
#pragma unroll
      for (int u = 0; u < 4; ++u)
#pragma unroll
        for (int v = 0; v < 4; ++v) acc[u][v] = fmaf(a[u], bv[v], acc[u][v]);
    }
    __syncthreads();
  }
#pragma unroll
  for (int u = 0; u < 4; ++u) {
#pragma unroll
    for (int v = 0; v < 4; ++v) {
      float val = acc[u][v];
      if (bias) val += bias[bn + tc + v];
      if (ACT == 1) val = val > 0.f ? val : 0.2f * val;
      C[(size_t)(bm + tr + u) * Nc + bn + tc + v] = val;
    }
  }
}

// ---------------- per-head L2 normalize + layout change + bf16 convert ----------
// MODE 0: L2-normalize per head (q and k). MODE 1: plain convert (v).
// in: f32 [B,N,H*DH]; out: bf16 [B,H,N,DH]
template <int MODE>
__global__ __launch_bounds__(512) void headnorm_cvt_kernel(
    const float* __restrict__ in, unsigned short* __restrict__ out) {
  int row = blockIdx.x;            // b*N + n
  int tid = threadIdx.x;           // wave (64 lanes) == one head (DH=64)
  int h = tid >> 6, d = tid & 63;
  size_t idx = (size_t)row * DD + tid;
  float v = in[idx];
  if (MODE == 0) {
    float ss = wave_sum(v * v);
    float nrm = fmaxf(sqrtf(ss), 1e-12f);
    v /= nrm;
  }
  int b = row >> 10, n = row & (NN - 1);
  out[(((size_t)b * HH + h) * NN + n) * DHH + d] = cvt_bf16(v);
}

// ---------------- MFMA flash attention ----------------
// q/k/v: bf16 [B,H,N,64] (q,k unit-norm). att out: f32 [B,N,H*DH].
// Block: 4 waves, 64 q-rows. Wave w owns q rows [w*16, w*16+16).
__global__ __launch_bounds__(256) void attn_mfma_kernel(
    const unsigned short* __restrict__ qb, const unsigned short* __restrict__ kb,
    const unsigned short* __restrict__ vb, const float* __restrict__ coords,
    const float* __restrict__ logit_scale,
    const float* __restrict__ W_r1, const float* __restrict__ b_r1,
    const float* __restrict__ W_r2, const float* __restrict__ b_r2,
    float* __restrict__ att) {
  int qt = blockIdx.x, h = blockIdx.y, b = blockIdx.z;
  int tid = threadIdx.x;
  int w = tid >> 6, lane = tid & 63;
  int lg = lane >> 4, lr = lane & 15;

  // Vt[d][k] (64x64 bf16) and per-wave P[q][k] (16x64 bf16), both XOR-swizzled:
  // element index ^= (row&7)<<3  (byte bits 4-6) -> conflict-free ds_read_b128.
  __shared__ unsigned short vt[64 * 64];
  __shared__ unsigned short pl[4 * 16 * 64];

  const size_t bh = ((size_t)b * HH + h) * NN;

  // Q A-frags: lane holds A[m=lr][k = lg*8+j], two d-slices.
  int q_glob = qt * 64 + w * 16 + lr;
  bf16x8 aq0 = *(const bf16x8*)&qb[(bh + q_glob) * DHH + lg * 8];
  bf16x8 aq1 = *(const bf16x8*)&qb[(bh + q_glob) * DHH + 32 + lg * 8];

  // coords for this lane's 4 output q-rows (C-layout rows lg*4+r)
  float ciq0[4], ciq1[4];
#pragma unroll
  for (int r = 0; r < 4; ++r) {
    int qg = qt * 64 + w * 16 + lg * 4 + r;
    ciq0[r] = coords[((size_t)b * NN + qg) * 2 + 0];
    ciq1[r] = coords[((size_t)b * NN + qg) * 2 + 1];
  }
  float scale_h = __expf(fminf(logit_scale[h], 4.605170185988091f));
  float br2h = b_r2[h];

  float m_run[4] = {-1e30f, -1e30f, -1e30f, -1e30f};
  float l_run[4] = {0.f, 0.f, 0.f, 0.f};
  f32x4 zf = {0.f, 0.f, 0.f, 0.f};
  f32x4 acc_o[4] = {zf, zf, zf, zf};

  for (int kt = 0; kt < NN / 64; ++kt) {
    __syncthreads();  // prev PV reads of vt done
    // stage V tile transposed into LDS (swizzled)
#pragma unroll
    for (int it = 0; it < 2; ++it) {
      int kl = it * 32 + (tid & 31);
      int d0 = (tid >> 5) * 8;
      bf16x8 vv = *(const bf16x8*)&vb[(bh + kt * 64 + kl) * DHH + d0];
#pragma unroll
      for (int j = 0; j < 8; ++j) {
        int d = d0 + j;
        vt[(d * 64 + kl) ^ ((d & 7) << 3)] = (unsigned short)vv[j];
      }
    }
    __syncthreads();  // vt ready

    // S = Q @ K^T  (per wave: 16q x 64k)
    f32x4 s_acc[4];
#pragma unroll
    for (int kc = 0; kc < 4; ++kc) {
      const unsigned short* krow = &kb[(bh + kt * 64 + kc * 16 + lr) * DHH + lg * 8];
      bf16x8 bk0 = *(const bf16x8*)krow;
      bf16x8 bk1 = *(const bf16x8*)(krow + 32);
      s_acc[kc] = __builtin_amdgcn_mfma_f32_16x16x32_bf16(aq0, bk0, zf, 0, 0, 0);
      s_acc[kc] = __builtin_amdgcn_mfma_f32_16x16x32_bf16(aq1, bk1, s_acc[kc], 0, 0, 0);
    }

    // scale + RPE bias MLP (weights via uniform scalar loads -> SGPRs)
#pragma unroll
    for (int kc = 0; kc < 4; ++kc) {
      int kg = kt * 64 + kc * 16 + lr;  // this lane's S column
      float ck0 = coords[((size_t)b * NN + kg) * 2 + 0];
      float ck1 = coords[((size_t)b * NN + kg) * 2 + 1];
#pragma unroll
      for (int r = 0; r < 4; ++r) {
        float r0 = ciq0[r] - ck0, r1 = ciq1[r] - ck1;
        float bias = br2h;
#pragma unroll
        for (int l = 0; l < 16; ++l) {
          float hv = fmaf(r0, W_r1[l], fmaf(r1, W_r1[16 + l], b_r1[l]));
          bias = fmaf(fmaxf(hv, 0.f), W_r2[l * HH + h], bias);
        }
        s_acc[kc][r] = s_acc[kc][r] * scale_h + bias;
      }
    }

    // online softmax (per q-row = (lg*4+r); row lives across 16 lanes lr)
    float pf[4][4];
#pragma unroll
    for (int r = 0; r < 4; ++r) {
      float mx = fmaxf(fmaxf(s_acc[0][r], s_acc[1][r]),
                       fmaxf(s_acc[2][r], s_acc[3][r]));
      mx = fmaxf(mx, __shfl_xor(mx, 1));
      mx = fmaxf(mx, __shfl_xor(mx, 2));
      mx = fmaxf(mx, __shfl_xor(mx, 4));
      mx = fmaxf(mx, __shfl_xor(mx, 8));
      float m_new = fmaxf(m_run[r], mx);
      float alpha = __expf(m_run[r] - m_new);
      m_run[r] = m_new;
      float ps = 0.f;
#pragma unroll
      for (int kc = 0; kc < 4; ++kc) {
        float p = __expf(s_acc[kc][r] - m_new);
        pf[kc][r] = p;
        ps += p;
      }
      l_run[r] = l_run[r] * alpha + ps;
#pragma unroll
      for (int ds = 0; ds < 4; ++ds) acc_o[ds][r] *= alpha;
    }

    // P -> bf16 -> per-wave LDS (swizzled); wave-local, no barrier needed
#pragma unroll
    for (int kc = 0; kc < 4; ++kc)
#pragma unroll
      for (int r = 0; r < 4; ++r) {
        int q = lg * 4 + r;
        pl[w * 1024 + ((q * 64 + kc * 16 + lr) ^ ((q & 7) << 3))] =
            cvt_bf16(pf[kc][r]);
      }

    // O += P @ V   (A = P[16q][32k], B = Vt -> V[32k][16d])
#pragma unroll
    for (int ka = 0; ka < 2; ++ka) {
      bf16x8 pa = *(const bf16x8*)&pl[w * 1024 +
          ((lr * 64 + ka * 32 + lg * 8) ^ ((lr & 7) << 3))];
#pragma unroll
      for (int ds = 0; ds < 4; ++ds) {
        int d = ds * 16 + lr;
        bf16x8 bv = *(const bf16x8*)&vt[(d * 64 + ka * 32 + lg * 8) ^ ((d & 7) << 3)];
        acc_o[ds] = __builtin_amdgcn_mfma_f32_16x16x32_bf16(pa, bv, acc_o[ds], 0, 0, 0);
      }
    }
  }

  // final row-sum reduce + store
#pragma unroll
  for (int r = 0; r < 4; ++r) {
    l_run[r] += __shfl_xor(l_run[r], 1);
    l_run[r] += __shfl_xor(l_run[r], 2);
    l_run[r] += __shfl_xor(l_run[r], 4);
    l_run[r] += __shfl_xor(l_run[r], 8);
  }
#pragma unroll
  for (int ds = 0; ds < 4; ++ds)
#pragma unroll
    for (int r = 0; r < 4; ++r) {
      int qg = qt * 64 + w * 16 + lg * 4 + r;
      att[((size_t)b * NN + qg) * DD + h * DHH + ds * 16 + lr] =
          acc_o[ds][r] / l_run[r];
    }
}

// ---------------- launcher ----------------
extern "C" void kernel_launch(void* const* d_in, const int* in_sizes, int n_in,
                              void* d_out, int out_size, void* d_ws, size_t ws_size,
                              hipStream_t stream) {
  const float* x      = (const float*)d_in[0];
  const float* coords = (const float*)d_in[1];
  const float* Wq = (const float*)d_in[2];  const float* bq = (const float*)d_in[3];
  const float* Wk = (const float*)d_in[4];  const float* bk = (const float*)d_in[5];
  const float* Wv = (const float*)d_in[6];  const float* bv = (const float*)d_in[7];
  const float* Wo = (const float*)d_in[8];  const float* bo = (const float*)d_in[9];
  const float* logit_scale = (const float*)d_in[10];
  const float* W_pe = (const float*)d_in[11]; const float* b_pe = (const float*)d_in[12];
  const float* W_r1 = (const float*)d_in[13]; const float* b_r1 = (const float*)d_in[14];
  const float* W_r2 = (const float*)d_in[15]; const float* b_r2 = (const float*)d_in[16];
  const float* g_peq = (const float*)d_in[17]; const float* bt_peq = (const float*)d_in[18];
  const float* g_pek = (const float*)d_in[19]; const float* bt_pek = (const float*)d_in[20];
  const float* g2 = (const float*)d_in[21]; const float* bt2 = (const float*)d_in[22];
  const float* g3 = (const float*)d_in[23]; const float* bt3 = (const float*)d_in[24];
  const float* W_ff1 = (const float*)d_in[25];
  const float* W_ff2 = (const float*)d_in[26];
  float* out = (float*)d_out;

  const size_t T = (size_t)BB * NN;      // 4096 rows
  const size_t SL = T * DD;              // 2M floats per [B,N,D] slab
  float* ws = (float*)d_ws;
  // slab timeline (write-before-read verified):
  // s0: q_ln -> {q_bf,k_bf} -> proj   s1: k_ln -> v_bf -> x1
  // s2: qp -> hid[0..)  s3: kp  s4: vp  s5: att  s6: mlp
  float* q_ln = ws + 0 * SL;
  float* k_ln = ws + 1 * SL;
  float* qp   = ws + 2 * SL;
  float* kp   = ws + 3 * SL;
  float* vp   = ws + 4 * SL;
  float* att  = ws + 5 * SL;
  float* mlp  = ws + 6 * SL;
  float* proj = ws + 0 * SL;
  float* x1   = ws + 1 * SL;
  float* hid  = ws + 2 * SL;
  unsigned short* q_bf = (unsigned short*)(ws + 0 * SL);
  unsigned short* k_bf = q_bf + (size_t)BB * HH * NN * DHH;   // +4MB
  unsigned short* v_bf = (unsigned short*)(ws + 1 * SL);

  pe_ln_kernel<<<dim3(T), dim3(512), 0, stream>>>(
      x, coords, W_pe, b_pe, g_peq, bt_peq, g_pek, bt_pek, q_ln, k_ln);

  gemm_kernel<0><<<dim3(DD / 64, T / 64), dim3(256), 0, stream>>>(
      q_ln, Wq, bq, qp, (int)T, DD, DD);
  gemm_kernel<0><<<dim3(DD / 64, T / 64), dim3(256), 0, stream>>>(
      k_ln, Wk, bk, kp, (int)T, DD, DD);
  gemm_kernel<0><<<dim3(DD / 64, T / 64), dim3(256), 0, stream>>>(
      x, Wv, bv, vp, (int)T, DD, DD);

  headnorm_cvt_kernel<0><<<dim3(T), dim3(512), 0, stream>>>(qp, q_bf);
  headnorm_cvt_kernel<0><<<dim3(T), dim3(512), 0, stream>>>(kp, k_bf);
  headnorm_cvt_kernel<1><<<dim3(T), dim3(512), 0, stream>>>(vp, v_bf);

  attn_mfma_kernel<<<dim3(NN / 64, HH, BB), dim3(256), 0, stream>>>(
      q_bf, k_bf, v_bf, coords, logit_scale, W_r1, b_r1, W_r2, b_r2, att);

  gemm_kernel<0><<<dim3(DD / 64, T / 64), dim3(256), 0, stream>>>(
      att, Wo, bo, proj, (int)T, DD, DD);

  add_ln_kernel<<<dim3(T), dim3(512), 0, stream>>>(x, proj, g2, bt2, x1);

  gemm_kernel<1><<<dim3(FFF / 64, T / 64), dim3(256), 0, stream>>>(
      x1, W_ff1, nullptr, hid, (int)T, FFF, DD);
  gemm_kernel<1><<<dim3(DD / 64, T / 64), dim3(256), 0, stream>>>(
      hid, W_ff2, nullptr, mlp, (int)T, DD, FFF);

  add_ln_kernel<<<dim3(T), dim3(512), 0, stream>>>(x1, mlp, g3, bt3, out);
}

// Round 3
// 247.422 us; speedup vs baseline: 18.2323x; 2.8841x over previous
//
#include <hip/hip_runtime.h>

#define BB 4
#define NN 1024
#define DD 512
#define HH 8
#define DHH 64
#define FFF 2048

typedef __attribute__((ext_vector_type(8))) short bf16x8;
typedef __attribute__((ext_vector_type(4))) float f32x4;

__device__ inline float wave_sum(float v) {
#pragma unroll
  for (int off = 32; off; off >>= 1) v += __shfl_xor(v, off);
  return v;
}

__device__ inline unsigned short cvt_bf16(float f) {
  union { float f; unsigned u; } x;
  x.f = f;
  unsigned r = x.u + 0x7FFFu + ((x.u >> 16) & 1u);
  return (unsigned short)(r >> 16);
}

__device__ __forceinline__ void gl_lds16(const void* g, void* l) {
  __builtin_amdgcn_global_load_lds(
      (__attribute__((address_space(1))) void*)(g),
      (__attribute__((address_space(3))) void*)(l), 16, 0, 0);
}

// ---------------- weight transpose + bf16 convert (all 6 weights, 1 launch) ----
// out layout: WqT | WkT | WvT | WoT | Wff1T | Wff2T, each [N][K] bf16
__global__ __launch_bounds__(256) void wconv_kernel(
    const float* __restrict__ W0, const float* __restrict__ W1,
    const float* __restrict__ W2, const float* __restrict__ W3,
    const float* __restrict__ W4, const float* __restrict__ W5,
    unsigned short* __restrict__ out) {
  int bidx = blockIdx.x;
  const float* W; unsigned short* Wt; int K, N, local;
  if (bidx < 256) {
    int sel = bidx >> 6; local = bidx & 63;
    W = sel == 0 ? W0 : sel == 1 ? W1 : sel == 2 ? W2 : W3;
    K = 512; N = 512; Wt = out + (size_t)sel * 262144;
  } else if (bidx < 512) {
    local = bidx - 256; W = W4; K = 512; N = 2048; Wt = out + 1048576;
  } else {
    local = bidx - 512; W = W5; K = 2048; N = 512; Wt = out + 2097152;
  }
  int ntn = N >> 6;
  int tn = (local & (ntn - 1)) << 6, tk = (local / ntn) << 6;
  __shared__ float tile[64][65];
  int tid = threadIdx.x;
#pragma unroll
  for (int i = 0; i < 16; ++i) {
    int e = tid + i * 256, kk = e >> 6, nn = e & 63;
    tile[kk][nn] = W[(size_t)(tk + kk) * N + tn + nn];
  }
  __syncthreads();
#pragma unroll
  for (int i = 0; i < 16; ++i) {
    int e = tid + i * 256, nn = e >> 6, kk = e & 63;
    Wt[(size_t)(tn + nn) * K + tk + kk] = cvt_bf16(tile[kk][nn]);
  }
}

// ---------------- PE add + dual LayerNorm -> bf16, plus bf16 copy of x --------
__global__ __launch_bounds__(512) void pe_ln_kernel(
    const float* __restrict__ x, const float* __restrict__ coords,
    const float* __restrict__ W_pe, const float* __restrict__ b_pe,
    const float* __restrict__ g_q, const float* __restrict__ bt_q,
    const float* __restrict__ g_k, const float* __restrict__ bt_k,
    unsigned short* __restrict__ q_lnb, unsigned short* __restrict__ k_lnb,
    unsigned short* __restrict__ x_bf) {
  int row = blockIdx.x;
  int tid = threadIdx.x;
  float c0 = coords[(size_t)row * 2 + 0];
  float c1 = coords[(size_t)row * 2 + 1];
  size_t idx = (size_t)row * DD + tid;
  float xv = x[idx];
  x_bf[idx] = cvt_bf16(xv);
  float val = xv + c0 * W_pe[tid] + c1 * W_pe[DD + tid] + b_pe[tid];

  __shared__ float ws[8], ws2[8];
  float s = wave_sum(val);
  if ((tid & 63) == 0) ws[tid >> 6] = s;
  __syncthreads();
  float mean = 0.f;
#pragma unroll
  for (int w = 0; w < 8; ++w) mean += ws[w];
  mean *= (1.f / DD);
  float dv = val - mean;
  float s2 = wave_sum(dv * dv);
  if ((tid & 63) == 0) ws2[tid >> 6] = s2;
  __syncthreads();
  float var = 0.f;
#pragma unroll
  for (int w = 0; w < 8; ++w) var += ws2[w];
  var *= (1.f / DD);
  float rstd = rsqrtf(var + 1e-5f);
  q_lnb[idx] = cvt_bf16(dv * rstd * g_q[tid] + bt_q[tid]);
  k_lnb[idx] = cvt_bf16(dv * rstd * g_k[tid] + bt_k[tid]);
}

// ---------------- residual add + LayerNorm (f32 out + optional bf16 out) ------
__global__ __launch_bounds__(512) void add_ln_kernel(
    const float* __restrict__ a, const float* __restrict__ r,
    const float* __restrict__ g, const float* __restrict__ bt,
    float* __restrict__ out, unsigned short* __restrict__ out_bf) {
  int row = blockIdx.x;
  int tid = threadIdx.x;
  size_t idx = (size_t)row * DD + tid;
  float val = a[idx] + r[idx];
  __shared__ float ws[8], ws2[8];
  float s = wave_sum(val);
  if ((tid & 63) == 0) ws[tid >> 6] = s;
  __syncthreads();
  float mean = 0.f;
#pragma unroll
  for (int w = 0; w < 8; ++w) mean += ws[w];
  mean *= (1.f / DD);
  float dv = val - mean;
  float s2 = wave_sum(dv * dv);
  if ((tid & 63) == 0) ws2[tid >> 6] = s2;
  __syncthreads();
  float var = 0.f;
#pragma unroll
  for (int w = 0; w < 8; ++w) var += ws2[w];
  var *= (1.f / DD);
  float rstd = rsqrtf(var + 1e-5f);
  float o = dv * rstd * g[tid] + bt[tid];
  out[idx] = o;
  if (out_bf) out_bf[idx] = cvt_bf16(o);
}

// ---------------- bf16 MFMA GEMM: C = act(A[M,K] @ BT[N,K]^T + bias) ----------
// 128x128 tile, BK=64, 4 waves (2x2), dbuf LDS 64KB, global_load_lds staging
// with inverse-swizzled source (T2 / rule #21): byte ^= (row&7)<<4 in 128B rows.
template <int ACT, int OBF>
__global__ __launch_bounds__(256) void mgemm_kernel(
    const unsigned short* __restrict__ A, const unsigned short* __restrict__ BT,
    const float* __restrict__ bias, void* __restrict__ C,
    int M, int Nc, int K) {
  __shared__ unsigned short lds[4][8192];  // [buf*2 + (0:A,1:B)][128*64]
  int tid = threadIdx.x;
  int w = tid >> 6, lane = tid & 63, lg = lane >> 4, lr = lane & 15;
  int bm = blockIdx.y * 128, bn = blockIdx.x * 128;
  int wr = w >> 1, wc = w & 1;

  int segl = lane >> 3;            // row within 1KB segment (8 rows of 128B)
  int cb = (lane & 7) << 4;        // byte col within row

  f32x4 zf = {0.f, 0.f, 0.f, 0.f};
  f32x4 acc[4][4];
#pragma unroll
  for (int mi = 0; mi < 4; ++mi)
#pragma unroll
    for (int ni = 0; ni < 4; ++ni) acc[mi][ni] = zf;

  int nt = K >> 6;

  auto STAGE = [&](int buf, int t) {
    int k0 = t << 6;
#pragma unroll
    for (int i = 0; i < 4; ++i) {
      int seg = w * 4 + i;               // 16 segments per tile, 4 per wave
      int r = (seg << 3) + segl;
      int csw = cb ^ ((r & 7) << 4);
      const char* ga = (const char*)A + (((size_t)(bm + r) * K + k0) << 1) + csw;
      gl_lds16(ga, &lds[buf * 2][seg << 9]);
      const char* gb = (const char*)BT + (((size_t)(bn + r) * K + k0) << 1) + csw;
      gl_lds16(gb, &lds[buf * 2 + 1][seg << 9]);
    }
  };

  auto COMPUTE = [&](int buf) {
    const unsigned short* As = lds[buf * 2];
    const unsigned short* Bs = lds[buf * 2 + 1];
    bf16x8 af[2][4], bfr[2][4];
#pragma unroll
    for (int kh = 0; kh < 2; ++kh)
#pragma unroll
      for (int mi = 0; mi < 4; ++mi) {
        int r = wr * 64 + mi * 16 + lr;
        int e = (r << 6) + (kh << 5) + (lg << 3);
        af[kh][mi] = *(const bf16x8*)&As[e ^ ((r & 7) << 3)];
        int rb = wc * 64 + mi * 16 + lr;
        int eb = (rb << 6) + (kh << 5) + (lg << 3);
        bfr[kh][mi] = *(const bf16x8*)&Bs[eb ^ ((rb & 7) << 3)];
      }
#pragma unroll
    for (int kh = 0; kh < 2; ++kh)
#pragma unroll
      for (int mi = 0; mi < 4; ++mi)
#pragma unroll
        for (int ni = 0; ni < 4; ++ni)
          acc[mi][ni] = __builtin_amdgcn_mfma_f32_16x16x32_bf16(
              af[kh][mi], bfr[kh][ni], acc[mi][ni], 0, 0, 0);
  };

  STAGE(0, 0);
  __syncthreads();
  for (int t = 0; t < nt; ++t) {
    if (t + 1 < nt) STAGE((t + 1) & 1, t + 1);
    COMPUTE(t & 1);
    __syncthreads();
  }

#pragma unroll
  for (int ni = 0; ni < 4; ++ni) {
    int col = bn + wc * 64 + ni * 16 + lr;
    float bv = bias ? bias[col] : 0.f;
#pragma unroll
    for (int mi = 0; mi < 4; ++mi) {
#pragma unroll
      for (int j = 0; j < 4; ++j) {
        int row = bm + wr * 64 + mi * 16 + lg * 4 + j;
        float v = acc[mi][ni][j] + bv;
        if (ACT == 1) v = v > 0.f ? v : 0.2f * v;
        if (OBF)
          ((unsigned short*)C)[(size_t)row * Nc + col] = cvt_bf16(v);
        else
          ((float*)C)[(size_t)row * Nc + col] = v;
      }
    }
  }
}

// ---------------- per-head L2 normalize + layout change + bf16 convert --------
template <int MODE>
__global__ __launch_bounds__(512) void headnorm_cvt_kernel(
    const float* __restrict__ in, unsigned short* __restrict__ out) {
  int row = blockIdx.x;
  int tid = threadIdx.x;
  int h = tid >> 6, d = tid & 63;
  size_t idx = (size_t)row * DD + tid;
  float v = in[idx];
  if (MODE == 0) {
    float ss = wave_sum(v * v);
    float nrm = fmaxf(sqrtf(ss), 1e-12f);
    v /= nrm;
  }
  int b = row >> 10, n = row & (NN - 1);
  out[(((size_t)b * HH + h) * NN + n) * DHH + d] = cvt_bf16(v);
}

// ---------------- MFMA flash attention (bf16 out) ----------------
__global__ __launch_bounds__(256) void attn_mfma_kernel(
    const unsigned short* __restrict__ qb, const unsigned short* __restrict__ kb,
    const unsigned short* __restrict__ vb, const float* __restrict__ coords,
    const float* __restrict__ logit_scale,
    const float* __restrict__ W_r1, const float* __restrict__ b_r1,
    const float* __restrict__ W_r2, const float* __restrict__ b_r2,
    unsigned short* __restrict__ attb) {
  int qt = blockIdx.x, h = blockIdx.y, b = blockIdx.z;
  int tid = threadIdx.x;
  int w = tid >> 6, lane = tid & 63;
  int lg = lane >> 4, lr = lane & 15;

  __shared__ unsigned short vt[64 * 64];
  __shared__ unsigned short pl[4 * 16 * 64];

  const size_t bh = ((size_t)b * HH + h) * NN;

  int q_glob = qt * 64 + w * 16 + lr;
  bf16x8 aq0 = *(const bf16x8*)&qb[(bh + q_glob) * DHH + lg * 8];
  bf16x8 aq1 = *(const bf16x8*)&qb[(bh + q_glob) * DHH + 32 + lg * 8];

  float ciq0[4], ciq1[4];
#pragma unroll
  for (int r = 0; r < 4; ++r) {
    int qg = qt * 64 + w * 16 + lg * 4 + r;
    ciq0[r] = coords[((size_t)b * NN + qg) * 2 + 0];
    ciq1[r] = coords[((size_t)b * NN + qg) * 2 + 1];
  }
  float scale_h = __expf(fminf(logit_scale[h], 4.605170185988091f));
  float br2h = b_r2[h];

  float m_run[4] = {-1e30f, -1e30f, -1e30f, -1e30f};
  float l_run[4] = {0.f, 0.f, 0.f, 0.f};
  f32x4 zf = {0.f, 0.f, 0.f, 0.f};
  f32x4 acc_o[4] = {zf, zf, zf, zf};

  for (int kt = 0; kt < NN / 64; ++kt) {
    __syncthreads();
#pragma unroll
    for (int it = 0; it < 2; ++it) {
      int kl = it * 32 + (tid & 31);
      int d0 = (tid >> 5) * 8;
      bf16x8 vv = *(const bf16x8*)&vb[(bh + kt * 64 + kl) * DHH + d0];
#pragma unroll
      for (int j = 0; j < 8; ++j) {
        int d = d0 + j;
        vt[(d * 64 + kl) ^ ((d & 7) << 3)] = (unsigned short)vv[j];
      }
    }
    __syncthreads();

    f32x4 s_acc[4];
#pragma unroll
    for (int kc = 0; kc < 4; ++kc) {
      const unsigned short* krow = &kb[(bh + kt * 64 + kc * 16 + lr) * DHH + lg * 8];
      bf16x8 bk0 = *(const bf16x8*)krow;
      bf16x8 bk1 = *(const bf16x8*)(krow + 32);
      s_acc[kc] = __builtin_amdgcn_mfma_f32_16x16x32_bf16(aq0, bk0, zf, 0, 0, 0);
      s_acc[kc] = __builtin_amdgcn_mfma_f32_16x16x32_bf16(aq1, bk1, s_acc[kc], 0, 0, 0);
    }

#pragma unroll
    for (int kc = 0; kc < 4; ++kc) {
      int kg = kt * 64 + kc * 16 + lr;
      float ck0 = coords[((size_t)b * NN + kg) * 2 + 0];
      float ck1 = coords[((size_t)b * NN + kg) * 2 + 1];
#pragma unroll
      for (int r = 0; r < 4; ++r) {
        float r0 = ciq0[r] - ck0, r1 = ciq1[r] - ck1;
        float bias = br2h;
#pragma unroll
        for (int l = 0; l < 16; ++l) {
          float hv = fmaf(r0, W_r1[l], fmaf(r1, W_r1[16 + l], b_r1[l]));
          bias = fmaf(fmaxf(hv, 0.f), W_r2[l * HH + h], bias);
        }
        s_acc[kc][r] = s_acc[kc][r] * scale_h + bias;
      }
    }

    float pf[4][4];
#pragma unroll
    for (int r = 0; r < 4; ++r) {
      float mx = fmaxf(fmaxf(s_acc[0][r], s_acc[1][r]),
                       fmaxf(s_acc[2][r], s_acc[3][r]));
      mx = fmaxf(mx, __shfl_xor(mx, 1));
      mx = fmaxf(mx, __shfl_xor(mx, 2));
      mx = fmaxf(mx, __shfl_xor(mx, 4));
      mx = fmaxf(mx, __shfl_xor(mx, 8));
      float m_new = fmaxf(m_run[r], mx);
      float alpha = __expf(m_run[r] - m_new);
      m_run[r] = m_new;
      float ps = 0.f;
#pragma unroll
      for (int kc = 0; kc < 4; ++kc) {
        float p = __expf(s_acc[kc][r] - m_new);
        pf[kc][r] = p;
        ps += p;
      }
      l_run[r] = l_run[r] * alpha + ps;
#pragma unroll
      for (int ds = 0; ds < 4; ++ds) acc_o[ds][r] *= alpha;
    }

#pragma unroll
    for (int kc = 0; kc < 4; ++kc)
#pragma unroll
      for (int r = 0; r < 4; ++r) {
        int q = lg * 4 + r;
        pl[w * 1024 + ((q * 64 + kc * 16 + lr) ^ ((q & 7) << 3))] =
            cvt_bf16(pf[kc][r]);
      }

#pragma unroll
    for (int ka = 0; ka < 2; ++ka) {
      bf16x8 pa = *(const bf16x8*)&pl[w * 1024 +
          ((lr * 64 + ka * 32 + lg * 8) ^ ((lr & 7) << 3))];
#pragma unroll
      for (int ds = 0; ds < 4; ++ds) {
        int d = ds * 16 + lr;
        bf16x8 bv = *(const bf16x8*)&vt[(d * 64 + ka * 32 + lg * 8) ^ ((d & 7) << 3)];
        acc_o[ds] = __builtin_amdgcn_mfma_f32_16x16x32_bf16(pa, bv, acc_o[ds], 0, 0, 0);
      }
    }
  }

#pragma unroll
  for (int r = 0; r < 4; ++r) {
    l_run[r] += __shfl_xor(l_run[r], 1);
    l_run[r] += __shfl_xor(l_run[r], 2);
    l_run[r] += __shfl_xor(l_run[r], 4);
    l_run[r] += __shfl_xor(l_run[r], 8);
  }
#pragma unroll
  for (int ds = 0; ds < 4; ++ds)
#pragma unroll
    for (int r = 0; r < 4; ++r) {
      int qg = qt * 64 + w * 16 + lg * 4 + r;
      attb[((size_t)b * NN + qg) * DD + h * DHH + ds * 16 + lr] =
          cvt_bf16(acc_o[ds][r] / l_run[r]);
    }
}

// ---------------- launcher ----------------
extern "C" void kernel_launch(void* const* d_in, const int* in_sizes, int n_in,
                              void* d_out, int out_size, void* d_ws, size_t ws_size,
                              hipStream_t stream) {
  const float* x      = (const float*)d_in[0];
  const float* coords = (const float*)d_in[1];
  const float* Wq = (const float*)d_in[2];  const float* bq = (const float*)d_in[3];
  const float* Wk = (const float*)d_in[4];  const float* bk = (const float*)d_in[5];
  const float* Wv = (const float*)d_in[6];  const float* bv = (const float*)d_in[7];
  const float* Wo = (const float*)d_in[8];  const float* bo = (const float*)d_in[9];
  const float* logit_scale = (const float*)d_in[10];
  const float* W_pe = (const float*)d_in[11]; const float* b_pe = (const float*)d_in[12];
  const float* W_r1 = (const float*)d_in[13]; const float* b_r1 = (const float*)d_in[14];
  const float* W_r2 = (const float*)d_in[15]; const float* b_r2 = (const float*)d_in[16];
  const float* g_peq = (const float*)d_in[17]; const float* bt_peq = (const float*)d_in[18];
  const float* g_pek = (const float*)d_in[19]; const float* bt_pek = (const float*)d_in[20];
  const float* g2 = (const float*)d_in[21]; const float* bt2 = (const float*)d_in[22];
  const float* g3 = (const float*)d_in[23]; const float* bt3 = (const float*)d_in[24];
  const float* W_ff1 = (const float*)d_in[25];
  const float* W_ff2 = (const float*)d_in[26];
  float* out = (float*)d_out;

  const size_t T = (size_t)BB * NN;        // 4096 rows
  char* wsb = (char*)d_ws;
  const size_t U = 4u * 1024u * 1024u;     // 4MB unit = T*D*2B

  // weight transposes: [0, 2U)
  unsigned short* wt_all = (unsigned short*)(wsb + 0 * U);
  unsigned short* WqT   = wt_all;
  unsigned short* WkT   = wt_all + 262144;
  unsigned short* WvT   = wt_all + 524288;
  unsigned short* WoT   = wt_all + 786432;
  unsigned short* Wff1T = wt_all + 1048576;
  unsigned short* Wff2T = wt_all + 2097152;
  // activation timeline (write-before-read verified):
  unsigned short* q_lnb = (unsigned short*)(wsb + 2 * U);
  unsigned short* k_lnb = (unsigned short*)(wsb + 3 * U);
  unsigned short* x_bf  = (unsigned short*)(wsb + 4 * U);
  float* qp   = (float*)(wsb + 5 * U);     // [5U,7U)
  float* kp   = (float*)(wsb + 7 * U);     // [7U,9U)
  float* vp   = (float*)(wsb + 9 * U);     // [9U,11U)
  unsigned short* q_bf = (unsigned short*)(wsb + 2 * U);  // over q_lnb (dead)
  unsigned short* k_bf = (unsigned short*)(wsb + 3 * U);
  unsigned short* v_bf = (unsigned short*)(wsb + 4 * U);
  unsigned short* att_bf = (unsigned short*)(wsb + 5 * U); // over qp-lo (dead)
  float* proj = (float*)(wsb + 6 * U);     // [6U,8U) qp-hi/kp-lo dead
  float* x1   = (float*)(wsb + 8 * U);     // [8U,10U) kp-hi/vp-lo dead
  unsigned short* x1_bf = (unsigned short*)(wsb + 10 * U); // vp-hi dead
  unsigned short* hid_bf = (unsigned short*)(wsb + 2 * U); // [2U,6U) q/k/v/att_bf dead
  float* mlp  = (float*)(wsb + 6 * U);     // [6U,8U) proj dead

  wconv_kernel<<<dim3(768), dim3(256), 0, stream>>>(
      Wq, Wk, Wv, Wo, W_ff1, W_ff2, wt_all);

  pe_ln_kernel<<<dim3(T), dim3(512), 0, stream>>>(
      x, coords, W_pe, b_pe, g_peq, bt_peq, g_pek, bt_pek, q_lnb, k_lnb, x_bf);

  mgemm_kernel<0, 0><<<dim3(DD / 128, T / 128), dim3(256), 0, stream>>>(
      q_lnb, WqT, bq, qp, (int)T, DD, DD);
  mgemm_kernel<0, 0><<<dim3(DD / 128, T / 128), dim3(256), 0, stream>>>(
      k_lnb, WkT, bk, kp, (int)T, DD, DD);
  mgemm_kernel<0, 0><<<dim3(DD / 128, T / 128), dim3(256), 0, stream>>>(
      x_bf, WvT, bv, vp, (int)T, DD, DD);

  headnorm_cvt_kernel<0><<<dim3(T), dim3(512), 0, stream>>>(qp, q_bf);
  headnorm_cvt_kernel<0><<<dim3(T), dim3(512), 0, stream>>>(kp, k_bf);
  headnorm_cvt_kernel<1><<<dim3(T), dim3(512), 0, stream>>>(vp, v_bf);

  attn_mfma_kernel<<<dim3(NN / 64, HH, BB), dim3(256), 0, stream>>>(
      q_bf, k_bf, v_bf, coords, logit_scale, W_r1, b_r1, W_r2, b_r2, att_bf);

  mgemm_kernel<0, 0><<<dim3(DD / 128, T / 128), dim3(256), 0, stream>>>(
      att_bf, WoT, bo, proj, (int)T, DD, DD);

  add_ln_kernel<<<dim3(T), dim3(512), 0, stream>>>(x, proj, g2, bt2, x1, x1_bf);

  mgemm_kernel<1, 1><<<dim3(FFF / 128, T / 128), dim3(256), 0, stream>>>(
      x1_bf, Wff1T, nullptr, hid_bf, (int)T, FFF, DD);
  mgemm_kernel<1, 0><<<dim3(DD / 128, T / 128), dim3(256), 0, stream>>>(
      hid_bf, Wff2T, nullptr, mlp, (int)T, DD, FFF);

  add_ln_kernel<<<dim3(T), dim3(512), 0, stream>>>(x1, mlp, g3, bt3, out, nullptr);
}

// Round 4
// 208.711 us; speedup vs baseline: 21.6140x; 1.1855x over previous
//
#include <hip/hip_runtime.h>

#define BB 4
#define NN 1024
#define DD 512
#define HH 8
#define DHH 64
#define FFF 2048

typedef __attribute__((ext_vector_type(8))) short bf16x8;
typedef __attribute__((ext_vector_type(4))) float f32x4;

__device__ inline float wave_sum(float v) {
#pragma unroll
  for (int off = 32; off; off >>= 1) v += __shfl_xor(v, off);
  return v;
}

__device__ inline unsigned short cvt_bf16(float f) {
  union { float f; unsigned u; } x;
  x.f = f;
  unsigned r = x.u + 0x7FFFu + ((x.u >> 16) & 1u);
  return (unsigned short)(r >> 16);
}

__device__ __forceinline__ void gl_lds16(const void* g, void* l) {
  __builtin_amdgcn_global_load_lds(
      (__attribute__((address_space(1))) void*)(g),
      (__attribute__((address_space(3))) void*)(l), 16, 0, 0);
}

// ---------------- weight transpose + bf16 convert (all 6 weights, 1 launch) ----
__global__ __launch_bounds__(256) void wconv_kernel(
    const float* __restrict__ W0, const float* __restrict__ W1,
    const float* __restrict__ W2, const float* __restrict__ W3,
    const float* __restrict__ W4, const float* __restrict__ W5,
    unsigned short* __restrict__ out) {
  int bidx = blockIdx.x;
  const float* W; unsigned short* Wt; int K, N, local;
  if (bidx < 256) {
    int sel = bidx >> 6; local = bidx & 63;
    W = sel == 0 ? W0 : sel == 1 ? W1 : sel == 2 ? W2 : W3;
    K = 512; N = 512; Wt = out + (size_t)sel * 262144;
  } else if (bidx < 512) {
    local = bidx - 256; W = W4; K = 512; N = 2048; Wt = out + 1048576;
  } else {
    local = bidx - 512; W = W5; K = 2048; N = 512; Wt = out + 2097152;
  }
  int ntn = N >> 6;
  int tn = (local & (ntn - 1)) << 6, tk = (local / ntn) << 6;
  __shared__ float tile[64][65];
  int tid = threadIdx.x;
#pragma unroll
  for (int i = 0; i < 16; ++i) {
    int e = tid + i * 256, kk = e >> 6, nn = e & 63;
    tile[kk][nn] = W[(size_t)(tk + kk) * N + tn + nn];
  }
  __syncthreads();
#pragma unroll
  for (int i = 0; i < 16; ++i) {
    int e = tid + i * 256, nn = e >> 6, kk = e & 63;
    Wt[(size_t)(tn + nn) * K + tk + kk] = cvt_bf16(tile[kk][nn]);
  }
}

// ---------------- RPE bias materialization: bias[nb,H,N,N] bf16 ----------------
// hidden layer computed ONCE per (q,k) pair (head-independent), 8 head-dots.
// hid[l] = relu(Aq[l] - Ck[l]);  Aq = cq@W1 + b1,  Ck = ck@W1.
__global__ __launch_bounds__(256) void bias_kernel(
    const float* __restrict__ coords,   // [nb,N,2] (batch offset by caller)
    const float* __restrict__ W_r1, const float* __restrict__ b_r1,
    const float* __restrict__ W_r2, const float* __restrict__ b_r2,
    unsigned short* __restrict__ bias_out) {
  int kt = blockIdx.x, qt = blockIdx.y, b = blockIdx.z;
  int tid = threadIdx.x;
  int q = qt * 64 + (tid >> 2);
  int k0 = kt * 32 + (tid & 3) * 8;
  float cq0 = coords[((size_t)b * NN + q) * 2 + 0];
  float cq1 = coords[((size_t)b * NN + q) * 2 + 1];
  float Aq[16];
#pragma unroll
  for (int l = 0; l < 16; ++l)
    Aq[l] = fmaf(cq0, W_r1[l], fmaf(cq1, W_r1[16 + l], b_r1[l]));
  float ck0[8], ck1[8];
#pragma unroll
  for (int kk = 0; kk < 8; ++kk) {
    ck0[kk] = coords[((size_t)b * NN + k0 + kk) * 2 + 0];
    ck1[kk] = coords[((size_t)b * NN + k0 + kk) * 2 + 1];
  }
  float acc[8][8];
#pragma unroll
  for (int kk = 0; kk < 8; ++kk)
#pragma unroll
    for (int h = 0; h < 8; ++h) acc[kk][h] = b_r2[h];
#pragma unroll
  for (int l = 0; l < 16; ++l) {
    float w1a = W_r1[l], w1b = W_r1[16 + l];
#pragma unroll
    for (int kk = 0; kk < 8; ++kk) {
      float hv = Aq[l] - fmaf(ck0[kk], w1a, ck1[kk] * w1b);
      hv = fmaxf(hv, 0.f);
#pragma unroll
      for (int h = 0; h < 8; ++h)
        acc[kk][h] = fmaf(hv, W_r2[l * HH + h], acc[kk][h]);
    }
  }
#pragma unroll
  for (int h = 0; h < 8; ++h) {
    bf16x8 ov;
#pragma unroll
    for (int kk = 0; kk < 8; ++kk) ov[kk] = (short)cvt_bf16(acc[kk][h]);
    *(bf16x8*)&bias_out[(((size_t)b * HH + h) * NN + q) * NN + k0] = ov;
  }
}

// ---------------- PE add + dual LayerNorm -> bf16, plus bf16 copy of x --------
__global__ __launch_bounds__(512) void pe_ln_kernel(
    const float* __restrict__ x, const float* __restrict__ coords,
    const float* __restrict__ W_pe, const float* __restrict__ b_pe,
    const float* __restrict__ g_q, const float* __restrict__ bt_q,
    const float* __restrict__ g_k, const float* __restrict__ bt_k,
    unsigned short* __restrict__ q_lnb, unsigned short* __restrict__ k_lnb,
    unsigned short* __restrict__ x_bf) {
  int row = blockIdx.x;
  int tid = threadIdx.x;
  float c0 = coords[(size_t)row * 2 + 0];
  float c1 = coords[(size_t)row * 2 + 1];
  size_t idx = (size_t)row * DD + tid;
  float xv = x[idx];
  x_bf[idx] = cvt_bf16(xv);
  float val = xv + c0 * W_pe[tid] + c1 * W_pe[DD + tid] + b_pe[tid];

  __shared__ float ws[8], ws2[8];
  float s = wave_sum(val);
  if ((tid & 63) == 0) ws[tid >> 6] = s;
  __syncthreads();
  float mean = 0.f;
#pragma unroll
  for (int w = 0; w < 8; ++w) mean += ws[w];
  mean *= (1.f / DD);
  float dv = val - mean;
  float s2 = wave_sum(dv * dv);
  if ((tid & 63) == 0) ws2[tid >> 6] = s2;
  __syncthreads();
  float var = 0.f;
#pragma unroll
  for (int w = 0; w < 8; ++w) var += ws2[w];
  var *= (1.f / DD);
  float rstd = rsqrtf(var + 1e-5f);
  q_lnb[idx] = cvt_bf16(dv * rstd * g_q[tid] + bt_q[tid]);
  k_lnb[idx] = cvt_bf16(dv * rstd * g_k[tid] + bt_k[tid]);
}

// ---------------- residual add + LayerNorm (f32 out + optional bf16 out) ------
__global__ __launch_bounds__(512) void add_ln_kernel(
    const float* __restrict__ a, const float* __restrict__ r,
    const float* __restrict__ g, const float* __restrict__ bt,
    float* __restrict__ out, unsigned short* __restrict__ out_bf) {
  int row = blockIdx.x;
  int tid = threadIdx.x;
  size_t idx = (size_t)row * DD + tid;
  float val = a[idx] + r[idx];
  __shared__ float ws[8], ws2[8];
  float s = wave_sum(val);
  if ((tid & 63) == 0) ws[tid >> 6] = s;
  __syncthreads();
  float mean = 0.f;
#pragma unroll
  for (int w = 0; w < 8; ++w) mean += ws[w];
  mean *= (1.f / DD);
  float dv = val - mean;
  float s2 = wave_sum(dv * dv);
  if ((tid & 63) == 0) ws2[tid >> 6] = s2;
  __syncthreads();
  float var = 0.f;
#pragma unroll
  for (int w = 0; w < 8; ++w) var += ws2[w];
  var *= (1.f / DD);
  float rstd = rsqrtf(var + 1e-5f);
  float o = dv * rstd * g[tid] + bt[tid];
  out[idx] = o;
  if (out_bf) out_bf[idx] = cvt_bf16(o);
}

// ---------------- bf16 MFMA GEMM: C = act(A[M,K] @ BT[N,K]^T + bias) ----------
template <int ACT, int OBF>
__global__ __launch_bounds__(256) void mgemm_kernel(
    const unsigned short* __restrict__ A, const unsigned short* __restrict__ BT,
    const float* __restrict__ bias, void* __restrict__ C,
    int M, int Nc, int K) {
  __shared__ unsigned short lds[4][8192];
  int tid = threadIdx.x;
  int w = tid >> 6, lane = tid & 63, lg = lane >> 4, lr = lane & 15;
  int bm = blockIdx.y * 128, bn = blockIdx.x * 128;
  int wr = w >> 1, wc = w & 1;

  int segl = lane >> 3;
  int cb = (lane & 7) << 4;

  f32x4 zf = {0.f, 0.f, 0.f, 0.f};
  f32x4 acc[4][4];
#pragma unroll
  for (int mi = 0; mi < 4; ++mi)
#pragma unroll
    for (int ni = 0; ni < 4; ++ni) acc[mi][ni] = zf;

  int nt = K >> 6;

  auto STAGE = [&](int buf, int t) {
    int k0 = t << 6;
#pragma unroll
    for (int i = 0; i < 4; ++i) {
      int seg = w * 4 + i;
      int r = (seg << 3) + segl;
      int csw = cb ^ ((r & 7) << 4);
      const char* ga = (const char*)A + (((size_t)(bm + r) * K + k0) << 1) + csw;
      gl_lds16(ga, &lds[buf * 2][seg << 9]);
      const char* gb = (const char*)BT + (((size_t)(bn + r) * K + k0) << 1) + csw;
      gl_lds16(gb, &lds[buf * 2 + 1][seg << 9]);
    }
  };

  auto COMPUTE = [&](int buf) {
    const unsigned short* As = lds[buf * 2];
    const unsigned short* Bs = lds[buf * 2 + 1];
    bf16x8 af[2][4], bfr[2][4];
#pragma unroll
    for (int kh = 0; kh < 2; ++kh)
#pragma unroll
      for (int mi = 0; mi < 4; ++mi) {
        int r = wr * 64 + mi * 16 + lr;
        int e = (r << 6) + (kh << 5) + (lg << 3);
        af[kh][mi] = *(const bf16x8*)&As[e ^ ((r & 7) << 3)];
        int rb = wc * 64 + mi * 16 + lr;
        int eb = (rb << 6) + (kh << 5) + (lg << 3);
        bfr[kh][mi] = *(const bf16x8*)&Bs[eb ^ ((rb & 7) << 3)];
      }
#pragma unroll
    for (int kh = 0; kh < 2; ++kh)
#pragma unroll
      for (int mi = 0; mi < 4; ++mi)
#pragma unroll
        for (int ni = 0; ni < 4; ++ni)
          acc[mi][ni] = __builtin_amdgcn_mfma_f32_16x16x32_bf16(
              af[kh][mi], bfr[kh][ni], acc[mi][ni], 0, 0, 0);
  };

  STAGE(0, 0);
  __syncthreads();
  for (int t = 0; t < nt; ++t) {
    if (t + 1 < nt) STAGE((t + 1) & 1, t + 1);
    COMPUTE(t & 1);
    __syncthreads();
  }

#pragma unroll
  for (int ni = 0; ni < 4; ++ni) {
    int col = bn + wc * 64 + ni * 16 + lr;
    float bv = bias ? bias[col] : 0.f;
#pragma unroll
    for (int mi = 0; mi < 4; ++mi) {
#pragma unroll
      for (int j = 0; j < 4; ++j) {
        int row = bm + wr * 64 + mi * 16 + lg * 4 + j;
        float v = acc[mi][ni][j] + bv;
        if (ACT == 1) v = v > 0.f ? v : 0.2f * v;
        if (OBF)
          ((unsigned short*)C)[(size_t)row * Nc + col] = cvt_bf16(v);
        else
          ((float*)C)[(size_t)row * Nc + col] = v;
      }
    }
  }
}

// ---------------- per-head L2 normalize + layout change + bf16 convert --------
template <int MODE>
__global__ __launch_bounds__(512) void headnorm_cvt_kernel(
    const float* __restrict__ in, unsigned short* __restrict__ out) {
  int row = blockIdx.x;
  int tid = threadIdx.x;
  int h = tid >> 6, d = tid & 63;
  size_t idx = (size_t)row * DD + tid;
  float v = in[idx];
  if (MODE == 0) {
    float ss = wave_sum(v * v);
    float nrm = fmaxf(sqrtf(ss), 1e-12f);
    v /= nrm;
  }
  int b = row >> 10, n = row & (NN - 1);
  out[(((size_t)b * HH + h) * NN + n) * DHH + d] = cvt_bf16(v);
}

// ---------------- MFMA flash attention with precomputed bias ----------------
__global__ __launch_bounds__(256) void attn_mfma_kernel(
    const unsigned short* __restrict__ qb, const unsigned short* __restrict__ kb,
    const unsigned short* __restrict__ vb,
    const unsigned short* __restrict__ bias_g,   // [nb,H,N,N] bf16
    const float* __restrict__ logit_scale,
    unsigned short* __restrict__ attb) {
  int qt = blockIdx.x, h = blockIdx.y, b = blockIdx.z;
  int tid = threadIdx.x;
  int w = tid >> 6, lane = tid & 63;
  int lg = lane >> 4, lr = lane & 15;

  __shared__ unsigned short vt[64 * 64];
  __shared__ unsigned short pl[4 * 16 * 64];

  const size_t bh = ((size_t)b * HH + h) * NN;

  int q_glob = qt * 64 + w * 16 + lr;
  bf16x8 aq0 = *(const bf16x8*)&qb[(bh + q_glob) * DHH + lg * 8];
  bf16x8 aq1 = *(const bf16x8*)&qb[(bh + q_glob) * DHH + 32 + lg * 8];

  // bias row pointers for this lane's 4 output q-rows
  const unsigned short* brow[4];
#pragma unroll
  for (int r = 0; r < 4; ++r) {
    int qg = qt * 64 + w * 16 + lg * 4 + r;
    brow[r] = &bias_g[(bh + qg) * NN + lr];
  }
  float scale_h = __expf(fminf(logit_scale[h], 4.605170185988091f));

  float m_run[4] = {-1e30f, -1e30f, -1e30f, -1e30f};
  float l_run[4] = {0.f, 0.f, 0.f, 0.f};
  f32x4 zf = {0.f, 0.f, 0.f, 0.f};
  f32x4 acc_o[4] = {zf, zf, zf, zf};

  for (int kt = 0; kt < NN / 64; ++kt) {
    // issue bias loads early (overlap with V staging + QK)
    unsigned short bu[4][4];
#pragma unroll
    for (int r = 0; r < 4; ++r)
#pragma unroll
      for (int kc = 0; kc < 4; ++kc) bu[kc][r] = brow[r][kt * 64 + kc * 16];

    __syncthreads();
#pragma unroll
    for (int it = 0; it < 2; ++it) {
      int kl = it * 32 + (tid & 31);
      int d0 = (tid >> 5) * 8;
      bf16x8 vv = *(const bf16x8*)&vb[(bh + kt * 64 + kl) * DHH + d0];
#pragma unroll
      for (int j = 0; j < 8; ++j) {
        int d = d0 + j;
        vt[(d * 64 + kl) ^ ((d & 7) << 3)] = (unsigned short)vv[j];
      }
    }
    __syncthreads();

    f32x4 s_acc[4];
#pragma unroll
    for (int kc = 0; kc < 4; ++kc) {
      const unsigned short* krow = &kb[(bh + kt * 64 + kc * 16 + lr) * DHH + lg * 8];
      bf16x8 bk0 = *(const bf16x8*)krow;
      bf16x8 bk1 = *(const bf16x8*)(krow + 32);
      s_acc[kc] = __builtin_amdgcn_mfma_f32_16x16x32_bf16(aq0, bk0, zf, 0, 0, 0);
      s_acc[kc] = __builtin_amdgcn_mfma_f32_16x16x32_bf16(aq1, bk1, s_acc[kc], 0, 0, 0);
    }

    // scale + precomputed bias
#pragma unroll
    for (int kc = 0; kc < 4; ++kc)
#pragma unroll
      for (int r = 0; r < 4; ++r) {
        float bf_ = __uint_as_float(((unsigned)bu[kc][r]) << 16);
        s_acc[kc][r] = fmaf(s_acc[kc][r], scale_h, bf_);
      }

    float pf[4][4];
#pragma unroll
    for (int r = 0; r < 4; ++r) {
      float mx = fmaxf(fmaxf(s_acc[0][r], s_acc[1][r]),
                       fmaxf(s_acc[2][r], s_acc[3][r]));
      mx = fmaxf(mx, __shfl_xor(mx, 1));
      mx = fmaxf(mx, __shfl_xor(mx, 2));
      mx = fmaxf(mx, __shfl_xor(mx, 4));
      mx = fmaxf(mx, __shfl_xor(mx, 8));
      float m_new = fmaxf(m_run[r], mx);
      float alpha = __expf(m_run[r] - m_new);
      m_run[r] = m_new;
      float ps = 0.f;
#pragma unroll
      for (int kc = 0; kc < 4; ++kc) {
        float p = __expf(s_acc[kc][r] - m_new);
        pf[kc][r] = p;
        ps += p;
      }
      l_run[r] = l_run[r] * alpha + ps;
#pragma unroll
      for (int ds = 0; ds < 4; ++ds) acc_o[ds][r] *= alpha;
    }

#pragma unroll
    for (int kc = 0; kc < 4; ++kc)
#pragma unroll
      for (int r = 0; r < 4; ++r) {
        int q = lg * 4 + r;
        pl[w * 1024 + ((q * 64 + kc * 16 + lr) ^ ((q & 7) << 3))] =
            cvt_bf16(pf[kc][r]);
      }

#pragma unroll
    for (int ka = 0; ka < 2; ++ka) {
      bf16x8 pa = *(const bf16x8*)&pl[w * 1024 +
          ((lr * 64 + ka * 32 + lg * 8) ^ ((lr & 7) << 3))];
#pragma unroll
      for (int ds = 0; ds < 4; ++ds) {
        int d = ds * 16 + lr;
        bf16x8 bv = *(const bf16x8*)&vt[(d * 64 + ka * 32 + lg * 8) ^ ((d & 7) << 3)];
        acc_o[ds] = __builtin_amdgcn_mfma_f32_16x16x32_bf16(pa, bv, acc_o[ds], 0, 0, 0);
      }
    }
  }

#pragma unroll
  for (int r = 0; r < 4; ++r) {
    l_run[r] += __shfl_xor(l_run[r], 1);
    l_run[r] += __shfl_xor(l_run[r], 2);
    l_run[r] += __shfl_xor(l_run[r], 4);
    l_run[r] += __shfl_xor(l_run[r], 8);
  }
#pragma unroll
  for (int ds = 0; ds < 4; ++ds)
#pragma unroll
    for (int r = 0; r < 4; ++r) {
      int qg = qt * 64 + w * 16 + lg * 4 + r;
      attb[((size_t)b * NN + qg) * DD + h * DHH + ds * 16 + lr] =
          cvt_bf16(acc_o[ds][r] / l_run[r]);
    }
}

// ---------------- launcher ----------------
extern "C" void kernel_launch(void* const* d_in, const int* in_sizes, int n_in,
                              void* d_out, int out_size, void* d_ws, size_t ws_size,
                              hipStream_t stream) {
  const float* x      = (const float*)d_in[0];
  const float* coords = (const float*)d_in[1];
  const float* Wq = (const float*)d_in[2];  const float* bq = (const float*)d_in[3];
  const float* Wk = (const float*)d_in[4];  const float* bk = (const float*)d_in[5];
  const float* Wv = (const float*)d_in[6];  const float* bv = (const float*)d_in[7];
  const float* Wo = (const float*)d_in[8];  const float* bo = (const float*)d_in[9];
  const float* logit_scale = (const float*)d_in[10];
  const float* W_pe = (const float*)d_in[11]; const float* b_pe = (const float*)d_in[12];
  const float* W_r1 = (const float*)d_in[13]; const float* b_r1 = (const float*)d_in[14];
  const float* W_r2 = (const float*)d_in[15]; const float* b_r2 = (const float*)d_in[16];
  const float* g_peq = (const float*)d_in[17]; const float* bt_peq = (const float*)d_in[18];
  const float* g_pek = (const float*)d_in[19]; const float* bt_pek = (const float*)d_in[20];
  const float* g2 = (const float*)d_in[21]; const float* bt2 = (const float*)d_in[22];
  const float* g3 = (const float*)d_in[23]; const float* bt3 = (const float*)d_in[24];
  const float* W_ff1 = (const float*)d_in[25];
  const float* W_ff2 = (const float*)d_in[26];
  float* out = (float*)d_out;

  const size_t T = (size_t)BB * NN;
  char* wsb = (char*)d_ws;
  const size_t U = 4u * 1024u * 1024u;

  unsigned short* wt_all = (unsigned short*)(wsb + 0 * U);
  unsigned short* WqT   = wt_all;
  unsigned short* WkT   = wt_all + 262144;
  unsigned short* WvT   = wt_all + 524288;
  unsigned short* WoT   = wt_all + 786432;
  unsigned short* Wff1T = wt_all + 1048576;
  unsigned short* Wff2T = wt_all + 2097152;
  unsigned short* q_lnb = (unsigned short*)(wsb + 2 * U);
  unsigned short* k_lnb = (unsigned short*)(wsb + 3 * U);
  unsigned short* x_bf  = (unsigned short*)(wsb + 4 * U);
  float* qp   = (float*)(wsb + 5 * U);
  float* kp   = (float*)(wsb + 7 * U);
  float* vp   = (float*)(wsb + 9 * U);
  unsigned short* q_bf = (unsigned short*)(wsb + 2 * U);
  unsigned short* k_bf = (unsigned short*)(wsb + 3 * U);
  unsigned short* v_bf = (unsigned short*)(wsb + 4 * U);
  unsigned short* att_bf = (unsigned short*)(wsb + 5 * U);
  float* proj = (float*)(wsb + 6 * U);
  float* x1   = (float*)(wsb + 8 * U);
  unsigned short* x1_bf = (unsigned short*)(wsb + 10 * U);
  unsigned short* hid_bf = (unsigned short*)(wsb + 2 * U);
  float* mlp  = (float*)(wsb + 6 * U);

  const size_t bias_full = (size_t)BB * HH * NN * NN * 2;   // 64 MiB
  const int full_path = (ws_size >= 11 * U + bias_full) ? 1 : 0;
  // full: bias above live slabs; per-b: 16 MiB in dead window [6U,10U)
  unsigned short* bias_ws = full_path
      ? (unsigned short*)(wsb + 11 * U)
      : (unsigned short*)(wsb + 6 * U);

  wconv_kernel<<<dim3(768), dim3(256), 0, stream>>>(
      Wq, Wk, Wv, Wo, W_ff1, W_ff2, wt_all);

  pe_ln_kernel<<<dim3(T), dim3(512), 0, stream>>>(
      x, coords, W_pe, b_pe, g_peq, bt_peq, g_pek, bt_pek, q_lnb, k_lnb, x_bf);

  mgemm_kernel<0, 0><<<dim3(DD / 128, T / 128), dim3(256), 0, stream>>>(
      q_lnb, WqT, bq, qp, (int)T, DD, DD);
  mgemm_kernel<0, 0><<<dim3(DD / 128, T / 128), dim3(256), 0, stream>>>(
      k_lnb, WkT, bk, kp, (int)T, DD, DD);
  mgemm_kernel<0, 0><<<dim3(DD / 128, T / 128), dim3(256), 0, stream>>>(
      x_bf, WvT, bv, vp, (int)T, DD, DD);

  headnorm_cvt_kernel<0><<<dim3(T), dim3(512), 0, stream>>>(qp, q_bf);
  headnorm_cvt_kernel<0><<<dim3(T), dim3(512), 0, stream>>>(kp, k_bf);
  headnorm_cvt_kernel<1><<<dim3(T), dim3(512), 0, stream>>>(vp, v_bf);

  if (full_path) {
    bias_kernel<<<dim3(NN / 32, NN / 64, BB), dim3(256), 0, stream>>>(
        coords, W_r1, b_r1, W_r2, b_r2, bias_ws);
    attn_mfma_kernel<<<dim3(NN / 64, HH, BB), dim3(256), 0, stream>>>(
        q_bf, k_bf, v_bf, bias_ws, logit_scale, att_bf);
  } else {
    for (int b = 0; b < BB; ++b) {
      bias_kernel<<<dim3(NN / 32, NN / 64, 1), dim3(256), 0, stream>>>(
          coords + (size_t)b * NN * 2, W_r1, b_r1, W_r2, b_r2, bias_ws);
      attn_mfma_kernel<<<dim3(NN / 64, HH, 1), dim3(256), 0, stream>>>(
          q_bf + (size_t)b * HH * NN * DHH, k_bf + (size_t)b * HH * NN * DHH,
          v_bf + (size_t)b * HH * NN * DHH, bias_ws, logit_scale,
          att_bf + (size_t)b * NN * DD);
    }
  }

  mgemm_kernel<0, 0><<<dim3(DD / 128, T / 128), dim3(256), 0, stream>>>(
      att_bf, WoT, bo, proj, (int)T, DD, DD);

  add_ln_kernel<<<dim3(T), dim3(512), 0, stream>>>(x, proj, g2, bt2, x1, x1_bf);

  mgemm_kernel<1, 1><<<dim3(FFF / 128, T / 128), dim3(256), 0, stream>>>(
      x1_bf, Wff1T, nullptr, hid_bf, (int)T, FFF, DD);
  mgemm_kernel<1, 0><<<dim3(DD / 128, T / 128), dim3(256), 0, stream>>>(
      hid_bf, Wff2T, nullptr, mlp, (int)T, DD, FFF);

  add_ln_kernel<<<dim3(T), dim3(512), 0, stream>>>(x1, mlp, g3, bt3, out, nullptr);
}

// Round 5
// 202.354 us; speedup vs baseline: 22.2929x; 1.0314x over previous
//
#include <hip/hip_runtime.h>

#define BB 4
#define NN 1024
#define DD 512
#define HH 8
#define DHH 64
#define FFF 2048

typedef __attribute__((ext_vector_type(8))) short bf16x8;
typedef __attribute__((ext_vector_type(4))) float f32x4;

__device__ inline float wave_sum(float v) {
#pragma unroll
  for (int off = 32; off; off >>= 1) v += __shfl_xor(v, off);
  return v;
}

__device__ inline unsigned short cvt_bf16(float f) {
  union { float f; unsigned u; } x;
  x.f = f;
  unsigned r = x.u + 0x7FFFu + ((x.u >> 16) & 1u);
  return (unsigned short)(r >> 16);
}

__device__ __forceinline__ void gl_lds16(const void* g, void* l) {
  __builtin_amdgcn_global_load_lds(
      (__attribute__((address_space(1))) void*)(g),
      (__attribute__((address_space(3))) void*)(l), 16, 0, 0);
}

// ---------------- weight transpose + bf16 convert (all 6 weights, 1 launch) ----
__global__ __launch_bounds__(256) void wconv_kernel(
    const float* __restrict__ W0, const float* __restrict__ W1,
    const float* __restrict__ W2, const float* __restrict__ W3,
    const float* __restrict__ W4, const float* __restrict__ W5,
    unsigned short* __restrict__ out) {
  int bidx = blockIdx.x;
  const float* W; unsigned short* Wt; int K, N, local;
  if (bidx < 256) {
    int sel = bidx >> 6; local = bidx & 63;
    W = sel == 0 ? W0 : sel == 1 ? W1 : sel == 2 ? W2 : W3;
    K = 512; N = 512; Wt = out + (size_t)sel * 262144;
  } else if (bidx < 512) {
    local = bidx - 256; W = W4; K = 512; N = 2048; Wt = out + 1048576;
  } else {
    local = bidx - 512; W = W5; K = 2048; N = 512; Wt = out + 2097152;
  }
  int ntn = N >> 6;
  int tn = (local & (ntn - 1)) << 6, tk = (local / ntn) << 6;
  __shared__ float tile[64][65];
  int tid = threadIdx.x;
#pragma unroll
  for (int i = 0; i < 16; ++i) {
    int e = tid + i * 256, kk = e >> 6, nn = e & 63;
    tile[kk][nn] = W[(size_t)(tk + kk) * N + tn + nn];
  }
  __syncthreads();
#pragma unroll
  for (int i = 0; i < 16; ++i) {
    int e = tid + i * 256, nn = e >> 6, kk = e & 63;
    Wt[(size_t)(tn + nn) * K + tk + kk] = cvt_bf16(tile[kk][nn]);
  }
}

// ---------------- RPE bias materialization: bias[nb,H,N,N] bf16 ----------------
__global__ __launch_bounds__(256) void bias_kernel(
    const float* __restrict__ coords,
    const float* __restrict__ W_r1, const float* __restrict__ b_r1,
    const float* __restrict__ W_r2, const float* __restrict__ b_r2,
    unsigned short* __restrict__ bias_out) {
  int kt = blockIdx.x, qt = blockIdx.y, b = blockIdx.z;
  int tid = threadIdx.x;
  int q = qt * 64 + (tid >> 2);
  int k0 = kt * 32 + (tid & 3) * 8;
  float cq0 = coords[((size_t)b * NN + q) * 2 + 0];
  float cq1 = coords[((size_t)b * NN + q) * 2 + 1];
  float Aq[16];
#pragma unroll
  for (int l = 0; l < 16; ++l)
    Aq[l] = fmaf(cq0, W_r1[l], fmaf(cq1, W_r1[16 + l], b_r1[l]));
  float ck0[8], ck1[8];
#pragma unroll
  for (int kk = 0; kk < 8; ++kk) {
    ck0[kk] = coords[((size_t)b * NN + k0 + kk) * 2 + 0];
    ck1[kk] = coords[((size_t)b * NN + k0 + kk) * 2 + 1];
  }
  float acc[8][8];
#pragma unroll
  for (int kk = 0; kk < 8; ++kk)
#pragma unroll
    for (int h = 0; h < 8; ++h) acc[kk][h] = b_r2[h];
#pragma unroll
  for (int l = 0; l < 16; ++l) {
    float w1a = W_r1[l], w1b = W_r1[16 + l];
#pragma unroll
    for (int kk = 0; kk < 8; ++kk) {
      float hv = Aq[l] - fmaf(ck0[kk], w1a, ck1[kk] * w1b);
      hv = fmaxf(hv, 0.f);
#pragma unroll
      for (int h = 0; h < 8; ++h)
        acc[kk][h] = fmaf(hv, W_r2[l * HH + h], acc[kk][h]);
    }
  }
#pragma unroll
  for (int h = 0; h < 8; ++h) {
    bf16x8 ov;
#pragma unroll
    for (int kk = 0; kk < 8; ++kk) ov[kk] = (short)cvt_bf16(acc[kk][h]);
    *(bf16x8*)&bias_out[(((size_t)b * HH + h) * NN + q) * NN + k0] = ov;
  }
}

// ---------------- PE add + dual LayerNorm -> bf16, plus bf16 copy of x --------
__global__ __launch_bounds__(512) void pe_ln_kernel(
    const float* __restrict__ x, const float* __restrict__ coords,
    const float* __restrict__ W_pe, const float* __restrict__ b_pe,
    const float* __restrict__ g_q, const float* __restrict__ bt_q,
    const float* __restrict__ g_k, const float* __restrict__ bt_k,
    unsigned short* __restrict__ q_lnb, unsigned short* __restrict__ k_lnb,
    unsigned short* __restrict__ x_bf) {
  int row = blockIdx.x;
  int tid = threadIdx.x;
  float c0 = coords[(size_t)row * 2 + 0];
  float c1 = coords[(size_t)row * 2 + 1];
  size_t idx = (size_t)row * DD + tid;
  float xv = x[idx];
  x_bf[idx] = cvt_bf16(xv);
  float val = xv + c0 * W_pe[tid] + c1 * W_pe[DD + tid] + b_pe[tid];

  __shared__ float ws[8], ws2[8];
  float s = wave_sum(val);
  if ((tid & 63) == 0) ws[tid >> 6] = s;
  __syncthreads();
  float mean = 0.f;
#pragma unroll
  for (int w = 0; w < 8; ++w) mean += ws[w];
  mean *= (1.f / DD);
  float dv = val - mean;
  float s2 = wave_sum(dv * dv);
  if ((tid & 63) == 0) ws2[tid >> 6] = s2;
  __syncthreads();
  float var = 0.f;
#pragma unroll
  for (int w = 0; w < 8; ++w) var += ws2[w];
  var *= (1.f / DD);
  float rstd = rsqrtf(var + 1e-5f);
  q_lnb[idx] = cvt_bf16(dv * rstd * g_q[tid] + bt_q[tid]);
  k_lnb[idx] = cvt_bf16(dv * rstd * g_k[tid] + bt_k[tid]);
}

// ---------------- residual add + LayerNorm (f32 out + optional bf16 out) ------
__global__ __launch_bounds__(512) void add_ln_kernel(
    const float* __restrict__ a, const float* __restrict__ r,
    const float* __restrict__ g, const float* __restrict__ bt,
    float* __restrict__ out, unsigned short* __restrict__ out_bf) {
  int row = blockIdx.x;
  int tid = threadIdx.x;
  size_t idx = (size_t)row * DD + tid;
  float val = a[idx] + r[idx];
  __shared__ float ws[8], ws2[8];
  float s = wave_sum(val);
  if ((tid & 63) == 0) ws[tid >> 6] = s;
  __syncthreads();
  float mean = 0.f;
#pragma unroll
  for (int w = 0; w < 8; ++w) mean += ws[w];
  mean *= (1.f / DD);
  float dv = val - mean;
  float s2 = wave_sum(dv * dv);
  if ((tid & 63) == 0) ws2[tid >> 6] = s2;
  __syncthreads();
  float var = 0.f;
#pragma unroll
  for (int w = 0; w < 8; ++w) var += ws2[w];
  var *= (1.f / DD);
  float rstd = rsqrtf(var + 1e-5f);
  float o = dv * rstd * g[tid] + bt[tid];
  out[idx] = o;
  if (out_bf) out_bf[idx] = cvt_bf16(o);
}

// ---------------- bf16 MFMA GEMM: C = act(A[M,K] @ BT[N,K]^T + bias) ----------
// EPI: 0 = f32 row-major, 1 = bf16 row-major,
//      2 = head-L2-norm -> bf16 [B,H,N,64], 3 = cvt -> bf16 [B,H,N,64]
template <int ACT, int EPI>
__global__ __launch_bounds__(256) void mgemm_kernel(
    const unsigned short* __restrict__ A, const unsigned short* __restrict__ BT,
    const float* __restrict__ bias, void* __restrict__ C,
    int M, int Nc, int K) {
  __shared__ unsigned short lds[4][8192];
  int tid = threadIdx.x;
  int w = tid >> 6, lane = tid & 63, lg = lane >> 4, lr = lane & 15;
  int bm = blockIdx.y * 128, bn = blockIdx.x * 128;
  int wr = w >> 1, wc = w & 1;

  int segl = lane >> 3;
  int cb = (lane & 7) << 4;

  f32x4 zf = {0.f, 0.f, 0.f, 0.f};
  f32x4 acc[4][4];
#pragma unroll
  for (int mi = 0; mi < 4; ++mi)
#pragma unroll
    for (int ni = 0; ni < 4; ++ni) acc[mi][ni] = zf;

  int nt = K >> 6;

  auto STAGE = [&](int buf, int t) {
    int k0 = t << 6;
#pragma unroll
    for (int i = 0; i < 4; ++i) {
      int seg = w * 4 + i;
      int r = (seg << 3) + segl;
      int csw = cb ^ ((r & 7) << 4);
      const char* ga = (const char*)A + (((size_t)(bm + r) * K + k0) << 1) + csw;
      gl_lds16(ga, &lds[buf * 2][seg << 9]);
      const char* gb = (const char*)BT + (((size_t)(bn + r) * K + k0) << 1) + csw;
      gl_lds16(gb, &lds[buf * 2 + 1][seg << 9]);
    }
  };

  auto COMPUTE = [&](int buf) {
    const unsigned short* As = lds[buf * 2];
    const unsigned short* Bs = lds[buf * 2 + 1];
    bf16x8 af[2][4], bfr[2][4];
#pragma unroll
    for (int kh = 0; kh < 2; ++kh)
#pragma unroll
      for (int mi = 0; mi < 4; ++mi) {
        int r = wr * 64 + mi * 16 + lr;
        int e = (r << 6) + (kh << 5) + (lg << 3);
        af[kh][mi] = *(const bf16x8*)&As[e ^ ((r & 7) << 3)];
        int rb = wc * 64 + mi * 16 + lr;
        int eb = (rb << 6) + (kh << 5) + (lg << 3);
        bfr[kh][mi] = *(const bf16x8*)&Bs[eb ^ ((rb & 7) << 3)];
      }
#pragma unroll
    for (int kh = 0; kh < 2; ++kh)
#pragma unroll
      for (int mi = 0; mi < 4; ++mi)
#pragma unroll
        for (int ni = 0; ni < 4; ++ni)
          acc[mi][ni] = __builtin_amdgcn_mfma_f32_16x16x32_bf16(
              af[kh][mi], bfr[kh][ni], acc[mi][ni], 0, 0, 0);
  };

  STAGE(0, 0);
  __syncthreads();
  for (int t = 0; t < nt; ++t) {
    if (t + 1 < nt) STAGE((t + 1) & 1, t + 1);
    COMPUTE(t & 1);
    __syncthreads();
  }

  if (EPI <= 1) {
#pragma unroll
    for (int ni = 0; ni < 4; ++ni) {
      int col = bn + wc * 64 + ni * 16 + lr;
      float bv = bias ? bias[col] : 0.f;
#pragma unroll
      for (int mi = 0; mi < 4; ++mi) {
#pragma unroll
        for (int j = 0; j < 4; ++j) {
          int row = bm + wr * 64 + mi * 16 + lg * 4 + j;
          float v = acc[mi][ni][j] + bv;
          if (ACT == 1) v = v > 0.f ? v : 0.2f * v;
          if (EPI == 1)
            ((unsigned short*)C)[(size_t)row * Nc + col] = cvt_bf16(v);
          else
            ((float*)C)[(size_t)row * Nc + col] = v;
        }
      }
    }
  } else {
    // head-structured output: wave's col-block == one head (64 cols)
    int h = (bn >> 6) + wc;
    float bvf[4];
#pragma unroll
    for (int ni = 0; ni < 4; ++ni) bvf[ni] = bias[bn + wc * 64 + ni * 16 + lr];
#pragma unroll
    for (int mi = 0; mi < 4; ++mi) {
#pragma unroll
      for (int j = 0; j < 4; ++j) {
        float vals[4]; float ss = 0.f;
#pragma unroll
        for (int ni = 0; ni < 4; ++ni) {
          float v = acc[mi][ni][j] + bvf[ni];
          vals[ni] = v;
          ss = fmaf(v, v, ss);
        }
        float rn = 1.f;
        if (EPI == 2) {
          ss += __shfl_xor(ss, 1);
          ss += __shfl_xor(ss, 2);
          ss += __shfl_xor(ss, 4);
          ss += __shfl_xor(ss, 8);
          rn = 1.f / fmaxf(sqrtf(ss), 1e-12f);
        }
        int row = bm + wr * 64 + mi * 16 + lg * 4 + j;
        int b_ = row >> 10, n_ = row & (NN - 1);
        unsigned short* ob =
            (unsigned short*)C + (((size_t)b_ * HH + h) * NN + n_) * DHH;
#pragma unroll
        for (int ni = 0; ni < 4; ++ni)
          ob[ni * 16 + lr] = cvt_bf16(vals[ni] * rn);
      }
    }
  }
}

// ---------------- MFMA flash attention, dbuf LDS bias/V, optional k-split -----
// NSPLIT=1: direct write to attb.  NSPLIT=2: unnormalized bf16 partials + m,l.
template <int NSPLIT>
__global__ __launch_bounds__(256) void attn_mfma_kernel(
    const unsigned short* __restrict__ qb, const unsigned short* __restrict__ kb,
    const unsigned short* __restrict__ vb,
    const unsigned short* __restrict__ bias_g,   // [nb,H,N,N] bf16
    const float* __restrict__ logit_scale,
    unsigned short* __restrict__ attb,
    unsigned short* __restrict__ part, int nb) {
  int qt = blockIdx.x, h = blockIdx.y;
  int b = blockIdx.z % nb, sp = blockIdx.z / nb;
  int tid = threadIdx.x;
  int w = tid >> 6, lane = tid & 63;
  int lg = lane >> 4, lr = lane & 15;

  __shared__ unsigned short vt[2][4096];   // V^T tile, swizzled
  __shared__ unsigned short bt[2][4096];   // bias tile, swizzled
  __shared__ unsigned short pl[4][1024];   // per-wave P

  const size_t bh = ((size_t)b * HH + h) * NN;
  const int NT = (NN / 64) / NSPLIT;
  const int kt0 = sp * NT;

  int q_glob = qt * 64 + w * 16 + lr;
  bf16x8 aq0 = *(const bf16x8*)&qb[(bh + q_glob) * DHH + lg * 8];
  bf16x8 aq1 = *(const bf16x8*)&qb[(bh + q_glob) * DHH + 32 + lg * 8];

  float scale_h = __expf(fminf(logit_scale[h], 4.605170185988091f));

  float m_run[4] = {-1e30f, -1e30f, -1e30f, -1e30f};
  float l_run[4] = {0.f, 0.f, 0.f, 0.f};
  f32x4 zf = {0.f, 0.f, 0.f, 0.f};
  f32x4 acc_o[4] = {zf, zf, zf, zf};

  auto STAGE = [&](int buf, int t) {
    int ktg = kt0 + t;
    // V transpose staging (register path, proven swizzle)
#pragma unroll
    for (int it = 0; it < 2; ++it) {
      int kl = it * 32 + (tid & 31);
      int d0 = (tid >> 5) * 8;
      bf16x8 vv = *(const bf16x8*)&vb[(bh + ktg * 64 + kl) * DHH + d0];
#pragma unroll
      for (int j = 0; j < 8; ++j) {
        int d = d0 + j;
        vt[buf][(d * 64 + kl) ^ ((d & 7) << 3)] = (unsigned short)vv[j];
      }
    }
    // bias tile via global_load_lds: linear dest, inverse-swizzled source
#pragma unroll
    for (int c = 0; c < 2; ++c) {
      int seg = w * 2 + c;
      int ql = seg * 8 + (lane >> 3);
      int ks = ((lane & 7) * 8) ^ (((ql >> 2) & 3) << 4);
      const unsigned short* src =
          &bias_g[(bh + qt * 64 + ql) * NN + ktg * 64 + ks];
      gl_lds16(src, &bt[buf][seg * 512]);
    }
  };

  STAGE(0, 0);
  __syncthreads();

  for (int t = 0; t < NT; ++t) {
    int cur = t & 1;
    if (t + 1 < NT) STAGE(cur ^ 1, t + 1);
    int ktg = kt0 + t;

    f32x4 s_acc[4];
#pragma unroll
    for (int kc = 0; kc < 4; ++kc) {
      const unsigned short* krow =
          &kb[(bh + ktg * 64 + kc * 16 + lr) * DHH + lg * 8];
      bf16x8 bk0 = *(const bf16x8*)krow;
      bf16x8 bk1 = *(const bf16x8*)(krow + 32);
      s_acc[kc] = __builtin_amdgcn_mfma_f32_16x16x32_bf16(aq0, bk0, zf, 0, 0, 0);
      s_acc[kc] = __builtin_amdgcn_mfma_f32_16x16x32_bf16(aq1, bk1, s_acc[kc], 0, 0, 0);
    }

    // scale + bias from LDS (swizzled, conflict-free u16 reads)
#pragma unroll
    for (int kc = 0; kc < 4; ++kc)
#pragma unroll
      for (int r = 0; r < 4; ++r) {
        int qrow = w * 16 + lg * 4 + r;
        unsigned short ub =
            bt[cur][qrow * 64 + ((kc * 16 + lr) ^ (lg << 4))];
        float bf_ = __uint_as_float(((unsigned)ub) << 16);
        s_acc[kc][r] = fmaf(s_acc[kc][r], scale_h, bf_);
      }

    float pf[4][4];
#pragma unroll
    for (int r = 0; r < 4; ++r) {
      float mx = fmaxf(fmaxf(s_acc[0][r], s_acc[1][r]),
                       fmaxf(s_acc[2][r], s_acc[3][r]));
      mx = fmaxf(mx, __shfl_xor(mx, 1));
      mx = fmaxf(mx, __shfl_xor(mx, 2));
      mx = fmaxf(mx, __shfl_xor(mx, 4));
      mx = fmaxf(mx, __shfl_xor(mx, 8));
      float m_new = fmaxf(m_run[r], mx);
      float alpha = __expf(m_run[r] - m_new);
      m_run[r] = m_new;
      float ps = 0.f;
#pragma unroll
      for (int kc = 0; kc < 4; ++kc) {
        float p = __expf(s_acc[kc][r] - m_new);
        pf[kc][r] = p;
        ps += p;
      }
      l_run[r] = l_run[r] * alpha + ps;
#pragma unroll
      for (int ds = 0; ds < 4; ++ds) acc_o[ds][r] *= alpha;
    }

#pragma unroll
    for (int kc = 0; kc < 4; ++kc)
#pragma unroll
      for (int r = 0; r < 4; ++r) {
        int q = lg * 4 + r;
        pl[w][(q * 64 + kc * 16 + lr) ^ ((q & 7) << 3)] = cvt_bf16(pf[kc][r]);
      }

#pragma unroll
    for (int ka = 0; ka < 2; ++ka) {
      bf16x8 pa = *(const bf16x8*)&pl[w][(lr * 64 + ka * 32 + lg * 8) ^
                                         ((lr & 7) << 3)];
#pragma unroll
      for (int ds = 0; ds < 4; ++ds) {
        int d = ds * 16 + lr;
        bf16x8 bv =
            *(const bf16x8*)&vt[cur][(d * 64 + ka * 32 + lg * 8) ^ ((d & 7) << 3)];
        acc_o[ds] = __builtin_amdgcn_mfma_f32_16x16x32_bf16(pa, bv, acc_o[ds], 0, 0, 0);
      }
    }
    __syncthreads();
  }

#pragma unroll
  for (int r = 0; r < 4; ++r) {
    l_run[r] += __shfl_xor(l_run[r], 1);
    l_run[r] += __shfl_xor(l_run[r], 2);
    l_run[r] += __shfl_xor(l_run[r], 4);
    l_run[r] += __shfl_xor(l_run[r], 8);
  }

  if (NSPLIT == 1) {
#pragma unroll
    for (int ds = 0; ds < 4; ++ds)
#pragma unroll
      for (int r = 0; r < 4; ++r) {
        int qg = qt * 64 + w * 16 + lg * 4 + r;
        attb[((size_t)b * NN + qg) * DD + h * DHH + ds * 16 + lr] =
            cvt_bf16(acc_o[ds][r] / l_run[r]);
      }
  } else {
#pragma unroll
    for (int r = 0; r < 4; ++r) {
      int qg = qt * 64 + w * 16 + lg * 4 + r;
      size_t idx = ((size_t)(sp * nb + b) * HH + h) * NN + qg;
      unsigned short* pr = part + idx * 68;
#pragma unroll
      for (int ds = 0; ds < 4; ++ds)
        pr[ds * 16 + lr] = cvt_bf16(acc_o[ds][r]);
      if (lr == 0) {
        *(float*)(pr + 64) = m_run[r];
        *(float*)(pr + 66) = l_run[r];
      }
    }
  }
}

// ---------------- combine 2 k-split partials -> att bf16 ----------------------
__global__ __launch_bounds__(256) void combine_kernel(
    const unsigned short* __restrict__ part, unsigned short* __restrict__ attb,
    int nb) {
  int tid = threadIdx.x;
  int w = tid >> 6, d = tid & 63;
  int row = blockIdx.x * 4 + w;            // [0, nb*H*N)
  int b = row >> 13, rem = row & 8191, h = rem >> 10, n = rem & (NN - 1);
  size_t i0 = ((size_t)b * HH + h) * NN + n;
  size_t i1 = i0 + (size_t)nb * HH * NN;
  const unsigned short* p0 = part + i0 * 68;
  const unsigned short* p1 = part + i1 * 68;
  float m0 = *(const float*)(p0 + 64), l0 = *(const float*)(p0 + 66);
  float m1 = *(const float*)(p1 + 64), l1 = *(const float*)(p1 + 66);
  float ms = fmaxf(m0, m1);
  float w0 = __expf(m0 - ms), w1 = __expf(m1 - ms);
  float a0 = __uint_as_float(((unsigned)p0[d]) << 16);
  float a1 = __uint_as_float(((unsigned)p1[d]) << 16);
  float o = (a0 * w0 + a1 * w1) / (l0 * w0 + l1 * w1);
  attb[((size_t)b * NN + n) * DD + h * DHH + d] = cvt_bf16(o);
}

// ---------------- launcher ----------------
extern "C" void kernel_launch(void* const* d_in, const int* in_sizes, int n_in,
                              void* d_out, int out_size, void* d_ws, size_t ws_size,
                              hipStream_t stream) {
  const float* x      = (const float*)d_in[0];
  const float* coords = (const float*)d_in[1];
  const float* Wq = (const float*)d_in[2];  const float* bq = (const float*)d_in[3];
  const float* Wk = (const float*)d_in[4];  const float* bk = (const float*)d_in[5];
  const float* Wv = (const float*)d_in[6];  const float* bv = (const float*)d_in[7];
  const float* Wo = (const float*)d_in[8];  const float* bo = (const float*)d_in[9];
  const float* logit_scale = (const float*)d_in[10];
  const float* W_pe = (const float*)d_in[11]; const float* b_pe = (const float*)d_in[12];
  const float* W_r1 = (const float*)d_in[13]; const float* b_r1 = (const float*)d_in[14];
  const float* W_r2 = (const float*)d_in[15]; const float* b_r2 = (const float*)d_in[16];
  const float* g_peq = (const float*)d_in[17]; const float* bt_peq = (const float*)d_in[18];
  const float* g_pek = (const float*)d_in[19]; const float* bt_pek = (const float*)d_in[20];
  const float* g2 = (const float*)d_in[21]; const float* bt2 = (const float*)d_in[22];
  const float* g3 = (const float*)d_in[23]; const float* bt3 = (const float*)d_in[24];
  const float* W_ff1 = (const float*)d_in[25];
  const float* W_ff2 = (const float*)d_in[26];
  float* out = (float*)d_out;

  const size_t T = (size_t)BB * NN;
  char* wsb = (char*)d_ws;
  const size_t U = 4u * 1024u * 1024u;

  // layout (U = 4 MiB), write-before-read verified per stage:
  unsigned short* wt_all = (unsigned short*)(wsb + 0 * U);   // [0,2U) weights
  unsigned short* WqT   = wt_all;
  unsigned short* WkT   = wt_all + 262144;
  unsigned short* WvT   = wt_all + 524288;
  unsigned short* WoT   = wt_all + 786432;
  unsigned short* Wff1T = wt_all + 1048576;
  unsigned short* Wff2T = wt_all + 2097152;
  unsigned short* q_lnb = (unsigned short*)(wsb + 2 * U);
  unsigned short* k_lnb = (unsigned short*)(wsb + 3 * U);
  unsigned short* x_bf  = (unsigned short*)(wsb + 4 * U);
  unsigned short* q_bf  = (unsigned short*)(wsb + 5 * U);
  unsigned short* k_bf  = (unsigned short*)(wsb + 6 * U);
  unsigned short* v_bf  = (unsigned short*)(wsb + 7 * U);
  unsigned short* att_bf = (unsigned short*)(wsb + 8 * U);
  float* proj = (float*)(wsb + 9 * U);                        // [9U,11U)
  float* x1   = (float*)(wsb + 11 * U);                       // [11U,13U)
  unsigned short* x1_bf = (unsigned short*)(wsb + 13 * U);    // [13U,14U)
  unsigned short* hid_bf = (unsigned short*)(wsb + 2 * U);    // [2U,6U) dead by then
  float* mlp  = (float*)(wsb + 9 * U);                        // proj dead
  // attention-phase overlays (dead regions during attn):
  unsigned short* part_ws = (unsigned short*)(wsb + 2 * U);   // 8.5 MiB in [2U,5U)
  unsigned short* bias_ws = (unsigned short*)(wsb + 9 * U);   // 64 MiB in [9U,25U)

  const int full_path = (ws_size >= 25 * U) ? 1 : 0;

  wconv_kernel<<<dim3(768), dim3(256), 0, stream>>>(
      Wq, Wk, Wv, Wo, W_ff1, W_ff2, wt_all);

  pe_ln_kernel<<<dim3(T), dim3(512), 0, stream>>>(
      x, coords, W_pe, b_pe, g_peq, bt_peq, g_pek, bt_pek, q_lnb, k_lnb, x_bf);

  mgemm_kernel<0, 2><<<dim3(DD / 128, T / 128), dim3(256), 0, stream>>>(
      q_lnb, WqT, bq, q_bf, (int)T, DD, DD);
  mgemm_kernel<0, 2><<<dim3(DD / 128, T / 128), dim3(256), 0, stream>>>(
      k_lnb, WkT, bk, k_bf, (int)T, DD, DD);
  mgemm_kernel<0, 3><<<dim3(DD / 128, T / 128), dim3(256), 0, stream>>>(
      x_bf, WvT, bv, v_bf, (int)T, DD, DD);

  if (full_path) {
    bias_kernel<<<dim3(NN / 32, NN / 64, BB), dim3(256), 0, stream>>>(
        coords, W_r1, b_r1, W_r2, b_r2, bias_ws);
    attn_mfma_kernel<2><<<dim3(NN / 64, HH, 2 * BB), dim3(256), 0, stream>>>(
        q_bf, k_bf, v_bf, bias_ws, logit_scale, nullptr, part_ws, BB);
    combine_kernel<<<dim3(BB * HH * NN / 4), dim3(256), 0, stream>>>(
        part_ws, att_bf, BB);
  } else {
    // per-batch fallback: 16 MiB bias in [9U,13U), no k-split
    for (int b = 0; b < BB; ++b) {
      bias_kernel<<<dim3(NN / 32, NN / 64, 1), dim3(256), 0, stream>>>(
          coords + (size_t)b * NN * 2, W_r1, b_r1, W_r2, b_r2, bias_ws);
      attn_mfma_kernel<1><<<dim3(NN / 64, HH, 1), dim3(256), 0, stream>>>(
          q_bf + (size_t)b * HH * NN * DHH, k_bf + (size_t)b * HH * NN * DHH,
          v_bf + (size_t)b * HH * NN * DHH, bias_ws, logit_scale,
          att_bf + (size_t)b * NN * DD, nullptr, 1);
    }
  }

  mgemm_kernel<0, 0><<<dim3(DD / 128, T / 128), dim3(256), 0, stream>>>(
      att_bf, WoT, bo, proj, (int)T, DD, DD);

  add_ln_kernel<<<dim3(T), dim3(512), 0, stream>>>(x, proj, g2, bt2, x1, x1_bf);

  mgemm_kernel<1, 1><<<dim3(FFF / 128, T / 128), dim3(256), 0, stream>>>(
      x1_bf, Wff1T, nullptr, hid_bf, (int)T, FFF, DD);
  mgemm_kernel<1, 0><<<dim3(DD / 128, T / 128), dim3(256), 0, stream>>>(
      hid_bf, Wff2T, nullptr, mlp, (int)T, DD, FFF);

  add_ln_kernel<<<dim3(T), dim3(512), 0, stream>>>(x1, mlp, g3, bt3, out, nullptr);
}

// Round 6
// 198.075 us; speedup vs baseline: 22.7745x; 1.0216x over previous
//
#include <hip/hip_runtime.h>

#define BB 4
#define NN 1024
#define DD 512
#define HH 8
#define DHH 64
#define FFF 2048

typedef __attribute__((ext_vector_type(8))) short bf16x8;
typedef __attribute__((ext_vector_type(4))) float f32x4;

__device__ inline float wave_sum(float v) {
#pragma unroll
  for (int off = 32; off; off >>= 1) v += __shfl_xor(v, off);
  return v;
}

__device__ inline unsigned short cvt_bf16(float f) {
  union { float f; unsigned u; } x;
  x.f = f;
  unsigned r = x.u + 0x7FFFu + ((x.u >> 16) & 1u);
  return (unsigned short)(r >> 16);
}

__device__ __forceinline__ void gl_lds16(const void* g, void* l) {
  __builtin_amdgcn_global_load_lds(
      (__attribute__((address_space(1))) void*)(g),
      (__attribute__((address_space(3))) void*)(l), 16, 0, 0);
}

// ---------------- weight transpose + bf16 convert (all 6 weights, 1 launch) ----
__global__ __launch_bounds__(256) void wconv_kernel(
    const float* __restrict__ W0, const float* __restrict__ W1,
    const float* __restrict__ W2, const float* __restrict__ W3,
    const float* __restrict__ W4, const float* __restrict__ W5,
    unsigned short* __restrict__ out) {
  int bidx = blockIdx.x;
  const float* W; unsigned short* Wt; int K, N, local;
  if (bidx < 256) {
    int sel = bidx >> 6; local = bidx & 63;
    W = sel == 0 ? W0 : sel == 1 ? W1 : sel == 2 ? W2 : W3;
    K = 512; N = 512; Wt = out + (size_t)sel * 262144;
  } else if (bidx < 512) {
    local = bidx - 256; W = W4; K = 512; N = 2048; Wt = out + 1048576;
  } else {
    local = bidx - 512; W = W5; K = 2048; N = 512; Wt = out + 2097152;
  }
  int ntn = N >> 6;
  int tn = (local & (ntn - 1)) << 6, tk = (local / ntn) << 6;
  __shared__ float tile[64][65];
  int tid = threadIdx.x;
#pragma unroll
  for (int i = 0; i < 16; ++i) {
    int e = tid + i * 256, kk = e >> 6, nn = e & 63;
    tile[kk][nn] = W[(size_t)(tk + kk) * N + tn + nn];
  }
  __syncthreads();
#pragma unroll
  for (int i = 0; i < 16; ++i) {
    int e = tid + i * 256, nn = e >> 6, kk = e & 63;
    Wt[(size_t)(tn + nn) * K + tk + kk] = cvt_bf16(tile[kk][nn]);
  }
}

// ---------------- RPE bias materialization: bias[nb,H,N,N] bf16 ----------------
__global__ __launch_bounds__(256) void bias_kernel(
    const float* __restrict__ coords,
    const float* __restrict__ W_r1, const float* __restrict__ b_r1,
    const float* __restrict__ W_r2, const float* __restrict__ b_r2,
    unsigned short* __restrict__ bias_out) {
  int kt = blockIdx.x, qt = blockIdx.y, b = blockIdx.z;
  int tid = threadIdx.x;
  int q = qt * 64 + (tid >> 2);
  int k0 = kt * 32 + (tid & 3) * 8;
  float cq0 = coords[((size_t)b * NN + q) * 2 + 0];
  float cq1 = coords[((size_t)b * NN + q) * 2 + 1];
  float Aq[16];
#pragma unroll
  for (int l = 0; l < 16; ++l)
    Aq[l] = fmaf(cq0, W_r1[l], fmaf(cq1, W_r1[16 + l], b_r1[l]));
  float ck0[8], ck1[8];
#pragma unroll
  for (int kk = 0; kk < 8; ++kk) {
    ck0[kk] = coords[((size_t)b * NN + k0 + kk) * 2 + 0];
    ck1[kk] = coords[((size_t)b * NN + k0 + kk) * 2 + 1];
  }
  float acc[8][8];
#pragma unroll
  for (int kk = 0; kk < 8; ++kk)
#pragma unroll
    for (int h = 0; h < 8; ++h) acc[kk][h] = b_r2[h];
#pragma unroll
  for (int l = 0; l < 16; ++l) {
    float w1a = W_r1[l], w1b = W_r1[16 + l];
#pragma unroll
    for (int kk = 0; kk < 8; ++kk) {
      float hv = Aq[l] - fmaf(ck0[kk], w1a, ck1[kk] * w1b);
      hv = fmaxf(hv, 0.f);
#pragma unroll
      for (int h = 0; h < 8; ++h)
        acc[kk][h] = fmaf(hv, W_r2[l * HH + h], acc[kk][h]);
    }
  }
#pragma unroll
  for (int h = 0; h < 8; ++h) {
    bf16x8 ov;
#pragma unroll
    for (int kk = 0; kk < 8; ++kk) ov[kk] = (short)cvt_bf16(acc[kk][h]);
    *(bf16x8*)&bias_out[(((size_t)b * HH + h) * NN + q) * NN + k0] = ov;
  }
}

// ---------------- PE add + dual LayerNorm -> bf16, plus bf16 copy of x --------
__global__ __launch_bounds__(512) void pe_ln_kernel(
    const float* __restrict__ x, const float* __restrict__ coords,
    const float* __restrict__ W_pe, const float* __restrict__ b_pe,
    const float* __restrict__ g_q, const float* __restrict__ bt_q,
    const float* __restrict__ g_k, const float* __restrict__ bt_k,
    unsigned short* __restrict__ q_lnb, unsigned short* __restrict__ k_lnb,
    unsigned short* __restrict__ x_bf) {
  int row = blockIdx.x;
  int tid = threadIdx.x;
  float c0 = coords[(size_t)row * 2 + 0];
  float c1 = coords[(size_t)row * 2 + 1];
  size_t idx = (size_t)row * DD + tid;
  float xv = x[idx];
  x_bf[idx] = cvt_bf16(xv);
  float val = xv + c0 * W_pe[tid] + c1 * W_pe[DD + tid] + b_pe[tid];

  __shared__ float ws[8], ws2[8];
  float s = wave_sum(val);
  if ((tid & 63) == 0) ws[tid >> 6] = s;
  __syncthreads();
  float mean = 0.f;
#pragma unroll
  for (int w = 0; w < 8; ++w) mean += ws[w];
  mean *= (1.f / DD);
  float dv = val - mean;
  float s2 = wave_sum(dv * dv);
  if ((tid & 63) == 0) ws2[tid >> 6] = s2;
  __syncthreads();
  float var = 0.f;
#pragma unroll
  for (int w = 0; w < 8; ++w) var += ws2[w];
  var *= (1.f / DD);
  float rstd = rsqrtf(var + 1e-5f);
  q_lnb[idx] = cvt_bf16(dv * rstd * g_q[tid] + bt_q[tid]);
  k_lnb[idx] = cvt_bf16(dv * rstd * g_k[tid] + bt_k[tid]);
}

// ---------------- residual add + LayerNorm (f32 out + optional bf16 out) ------
__global__ __launch_bounds__(512) void add_ln_kernel(
    const float* __restrict__ a, const float* __restrict__ r,
    const float* __restrict__ g, const float* __restrict__ bt,
    float* __restrict__ out, unsigned short* __restrict__ out_bf) {
  int row = blockIdx.x;
  int tid = threadIdx.x;
  size_t idx = (size_t)row * DD + tid;
  float val = a[idx] + r[idx];
  __shared__ float ws[8], ws2[8];
  float s = wave_sum(val);
  if ((tid & 63) == 0) ws[tid >> 6] = s;
  __syncthreads();
  float mean = 0.f;
#pragma unroll
  for (int w = 0; w < 8; ++w) mean += ws[w];
  mean *= (1.f / DD);
  float dv = val - mean;
  float s2 = wave_sum(dv * dv);
  if ((tid & 63) == 0) ws2[tid >> 6] = s2;
  __syncthreads();
  float var = 0.f;
#pragma unroll
  for (int w = 0; w < 8; ++w) var += ws2[w];
  var *= (1.f / DD);
  float rstd = rsqrtf(var + 1e-5f);
  float o = dv * rstd * g[tid] + bt[tid];
  out[idx] = o;
  if (out_bf) out_bf[idx] = cvt_bf16(o);
}

// ---------------- bf16 MFMA GEMM: C = act(A[M,K] @ BT[N,K]^T + bias) ----------
// EPI: 0 = f32 row-major, 1 = bf16 row-major
template <int ACT, int EPI>
__global__ __launch_bounds__(256) void mgemm_kernel(
    const unsigned short* __restrict__ A, const unsigned short* __restrict__ BT,
    const float* __restrict__ bias, void* __restrict__ C,
    int M, int Nc, int K) {
  __shared__ unsigned short lds[4][8192];
  int tid = threadIdx.x;
  int w = tid >> 6, lane = tid & 63, lg = lane >> 4, lr = lane & 15;
  int bm = blockIdx.y * 128, bn = blockIdx.x * 128;
  int wr = w >> 1, wc = w & 1;

  int segl = lane >> 3;
  int cb = (lane & 7) << 4;

  f32x4 zf = {0.f, 0.f, 0.f, 0.f};
  f32x4 acc[4][4];
#pragma unroll
  for (int mi = 0; mi < 4; ++mi)
#pragma unroll
    for (int ni = 0; ni < 4; ++ni) acc[mi][ni] = zf;

  int nt = K >> 6;

  auto STAGE = [&](int buf, int t) {
    int k0 = t << 6;
#pragma unroll
    for (int i = 0; i < 4; ++i) {
      int seg = w * 4 + i;
      int r = (seg << 3) + segl;
      int csw = cb ^ ((r & 7) << 4);
      const char* ga = (const char*)A + (((size_t)(bm + r) * K + k0) << 1) + csw;
      gl_lds16(ga, &lds[buf * 2][seg << 9]);
      const char* gb = (const char*)BT + (((size_t)(bn + r) * K + k0) << 1) + csw;
      gl_lds16(gb, &lds[buf * 2 + 1][seg << 9]);
    }
  };

  auto COMPUTE = [&](int buf) {
    const unsigned short* As = lds[buf * 2];
    const unsigned short* Bs = lds[buf * 2 + 1];
    bf16x8 af[2][4], bfr[2][4];
#pragma unroll
    for (int kh = 0; kh < 2; ++kh)
#pragma unroll
      for (int mi = 0; mi < 4; ++mi) {
        int r = wr * 64 + mi * 16 + lr;
        int e = (r << 6) + (kh << 5) + (lg << 3);
        af[kh][mi] = *(const bf16x8*)&As[e ^ ((r & 7) << 3)];
        int rb = wc * 64 + mi * 16 + lr;
        int eb = (rb << 6) + (kh << 5) + (lg << 3);
        bfr[kh][mi] = *(const bf16x8*)&Bs[eb ^ ((rb & 7) << 3)];
      }
#pragma unroll
    for (int kh = 0; kh < 2; ++kh)
#pragma unroll
      for (int mi = 0; mi < 4; ++mi)
#pragma unroll
        for (int ni = 0; ni < 4; ++ni)
          acc[mi][ni] = __builtin_amdgcn_mfma_f32_16x16x32_bf16(
              af[kh][mi], bfr[kh][ni], acc[mi][ni], 0, 0, 0);
  };

  STAGE(0, 0);
  __syncthreads();
  for (int t = 0; t < nt; ++t) {
    if (t + 1 < nt) STAGE((t + 1) & 1, t + 1);
    COMPUTE(t & 1);
    __syncthreads();
  }

#pragma unroll
  for (int ni = 0; ni < 4; ++ni) {
    int col = bn + wc * 64 + ni * 16 + lr;
    float bv = bias ? bias[col] : 0.f;
#pragma unroll
    for (int mi = 0; mi < 4; ++mi) {
#pragma unroll
      for (int j = 0; j < 4; ++j) {
        int row = bm + wr * 64 + mi * 16 + lg * 4 + j;
        float v = acc[mi][ni][j] + bv;
        if (ACT == 1) v = v > 0.f ? v : 0.2f * v;
        if (EPI == 1)
          ((unsigned short*)C)[(size_t)row * Nc + col] = cvt_bf16(v);
        else
          ((float*)C)[(size_t)row * Nc + col] = v;
      }
    }
  }
}

// ---------------- fused QKV GEMM (z: 0=q norm, 1=k norm, 2=v -> V^T) ----------
__global__ __launch_bounds__(256) void qkv_gemm_kernel(
    const unsigned short* __restrict__ q_lnb,
    const unsigned short* __restrict__ k_lnb,
    const unsigned short* __restrict__ x_bf,
    const unsigned short* __restrict__ wt,   // WqT|WkT|WvT, 262144 apart
    const float* __restrict__ bq, const float* __restrict__ bk,
    const float* __restrict__ bv_,
    unsigned short* __restrict__ q_bf, unsigned short* __restrict__ k_bf,
    unsigned short* __restrict__ vt_g) {
  int z = blockIdx.z;
  const unsigned short* A = z == 0 ? q_lnb : z == 1 ? k_lnb : x_bf;
  const unsigned short* BT = wt + (size_t)z * 262144;
  const float* bias = z == 0 ? bq : z == 1 ? bk : bv_;

  __shared__ unsigned short lds[4][8192];
  int tid = threadIdx.x;
  int w = tid >> 6, lane = tid & 63, lg = lane >> 4, lr = lane & 15;
  int bm = blockIdx.y * 128, bn = blockIdx.x * 128;
  int wr = w >> 1, wc = w & 1;
  int segl = lane >> 3;
  int cb = (lane & 7) << 4;

  f32x4 zf = {0.f, 0.f, 0.f, 0.f};
  f32x4 acc[4][4];
#pragma unroll
  for (int mi = 0; mi < 4; ++mi)
#pragma unroll
    for (int ni = 0; ni < 4; ++ni) acc[mi][ni] = zf;

  auto STAGE = [&](int buf, int t) {
    int k0 = t << 6;
#pragma unroll
    for (int i = 0; i < 4; ++i) {
      int seg = w * 4 + i;
      int r = (seg << 3) + segl;
      int csw = cb ^ ((r & 7) << 4);
      const char* ga = (const char*)A + (((size_t)(bm + r) * DD + k0) << 1) + csw;
      gl_lds16(ga, &lds[buf * 2][seg << 9]);
      const char* gb = (const char*)BT + (((size_t)(bn + r) * DD + k0) << 1) + csw;
      gl_lds16(gb, &lds[buf * 2 + 1][seg << 9]);
    }
  };
  auto COMPUTE = [&](int buf) {
    const unsigned short* As = lds[buf * 2];
    const unsigned short* Bs = lds[buf * 2 + 1];
    bf16x8 af[2][4], bfr[2][4];
#pragma unroll
    for (int kh = 0; kh < 2; ++kh)
#pragma unroll
      for (int mi = 0; mi < 4; ++mi) {
        int r = wr * 64 + mi * 16 + lr;
        int e = (r << 6) + (kh << 5) + (lg << 3);
        af[kh][mi] = *(const bf16x8*)&As[e ^ ((r & 7) << 3)];
        int rb = wc * 64 + mi * 16 + lr;
        int eb = (rb << 6) + (kh << 5) + (lg << 3);
        bfr[kh][mi] = *(const bf16x8*)&Bs[eb ^ ((rb & 7) << 3)];
      }
#pragma unroll
    for (int kh = 0; kh < 2; ++kh)
#pragma unroll
      for (int mi = 0; mi < 4; ++mi)
#pragma unroll
        for (int ni = 0; ni < 4; ++ni)
          acc[mi][ni] = __builtin_amdgcn_mfma_f32_16x16x32_bf16(
              af[kh][mi], bfr[kh][ni], acc[mi][ni], 0, 0, 0);
  };

  STAGE(0, 0);
  __syncthreads();
  for (int t = 0; t < 8; ++t) {
    if (t + 1 < 8) STAGE((t + 1) & 1, t + 1);
    COMPUTE(t & 1);
    __syncthreads();
  }

  int h = (bn >> 6) + wc;   // wave's 64-col block == one head
  float bvf[4];
#pragma unroll
  for (int ni = 0; ni < 4; ++ni) bvf[ni] = bias[bn + wc * 64 + ni * 16 + lr];
#pragma unroll
  for (int mi = 0; mi < 4; ++mi) {
#pragma unroll
    for (int j = 0; j < 4; ++j) {
      float vals[4]; float ss = 0.f;
#pragma unroll
      for (int ni = 0; ni < 4; ++ni) {
        float v = acc[mi][ni][j] + bvf[ni];
        vals[ni] = v;
        ss = fmaf(v, v, ss);
      }
      int row = bm + wr * 64 + mi * 16 + lg * 4 + j;
      int b_ = row >> 10, n_ = row & (NN - 1);
      if (z <= 1) {
        ss += __shfl_xor(ss, 1);
        ss += __shfl_xor(ss, 2);
        ss += __shfl_xor(ss, 4);
        ss += __shfl_xor(ss, 8);
        float rn = 1.f / fmaxf(sqrtf(ss), 1e-12f);
        unsigned short* ob = (z == 0 ? q_bf : k_bf) +
                             (((size_t)b_ * HH + h) * NN + n_) * DHH;
#pragma unroll
        for (int ni = 0; ni < 4; ++ni)
          ob[ni * 16 + lr] = cvt_bf16(vals[ni] * rn);
      } else {
#pragma unroll
        for (int ni = 0; ni < 4; ++ni)
          vt_g[(((size_t)b_ * HH + h) * DHH + ni * 16 + lr) * NN + n_] =
              cvt_bf16(vals[ni]);
      }
    }
  }
}

// ---------------- barrier-free MFMA flash attention (per-wave pipelines) ------
// V^T global [B,H,64,N]; bias [nb,H,N,N]; per-wave LDS only for P transpose.
template <int NSPLIT>
__global__ __launch_bounds__(256) void attn_wave_kernel(
    const unsigned short* __restrict__ qb, const unsigned short* __restrict__ kb,
    const unsigned short* __restrict__ vtg,
    const unsigned short* __restrict__ bias_g,
    const float* __restrict__ logit_scale,
    unsigned short* __restrict__ attb,
    unsigned short* __restrict__ part, int nb) {
  int qt = blockIdx.x, h = blockIdx.y;
  int b = blockIdx.z % nb, sp = blockIdx.z / nb;
  int tid = threadIdx.x;
  int w = tid >> 6, lane = tid & 63;
  int lg = lane >> 4, lr = lane & 15;

  __shared__ unsigned short pl[4][1024];   // per-wave P, XOR-swizzled

  const size_t bh = ((size_t)b * HH + h) * NN;
  const size_t vbase = ((size_t)b * HH + h) * DHH * NN;
  const int NT = (NN / 64) / NSPLIT;
  const int kt0 = sp * NT;

  int q_glob = qt * 64 + w * 16 + lr;
  bf16x8 aq0 = *(const bf16x8*)&qb[(bh + q_glob) * DHH + lg * 8];
  bf16x8 aq1 = *(const bf16x8*)&qb[(bh + q_glob) * DHH + 32 + lg * 8];

  float scale_h = __expf(fminf(logit_scale[h], 4.605170185988091f));

  const unsigned short* brow[4];
#pragma unroll
  for (int r = 0; r < 4; ++r)
    brow[r] = &bias_g[(bh + qt * 64 + w * 16 + lg * 4 + r) * NN + lr];

  float m_run[4] = {-1e30f, -1e30f, -1e30f, -1e30f};
  float l_run[4] = {0.f, 0.f, 0.f, 0.f};
  f32x4 zf = {0.f, 0.f, 0.f, 0.f};
  f32x4 acc_o[4] = {zf, zf, zf, zf};

  // prefetch tile-0 bias
  unsigned short bu[4][4];
#pragma unroll
  for (int r = 0; r < 4; ++r)
#pragma unroll
    for (int kc = 0; kc < 4; ++kc) bu[kc][r] = brow[r][kt0 * 64 + kc * 16];

#pragma unroll 2
  for (int t = 0; t < NT; ++t) {
    int ktg = kt0 + t;

    // QK^T
    f32x4 s_acc[4];
#pragma unroll
    for (int kc = 0; kc < 4; ++kc) {
      const unsigned short* krow =
          &kb[(bh + ktg * 64 + kc * 16 + lr) * DHH + lg * 8];
      bf16x8 bk0 = *(const bf16x8*)krow;
      bf16x8 bk1 = *(const bf16x8*)(krow + 32);
      s_acc[kc] = __builtin_amdgcn_mfma_f32_16x16x32_bf16(aq0, bk0, zf, 0, 0, 0);
      s_acc[kc] = __builtin_amdgcn_mfma_f32_16x16x32_bf16(aq1, bk1, s_acc[kc], 0, 0, 0);
    }

    // prefetch next tile's bias while QK is in flight
    unsigned short bu2[4][4];
    if (t + 1 < NT) {
#pragma unroll
      for (int r = 0; r < 4; ++r)
#pragma unroll
        for (int kc = 0; kc < 4; ++kc)
          bu2[kc][r] = brow[r][(ktg + 1) * 64 + kc * 16];
    }

#pragma unroll
    for (int kc = 0; kc < 4; ++kc)
#pragma unroll
      for (int r = 0; r < 4; ++r) {
        float bf_ = __uint_as_float(((unsigned)bu[kc][r]) << 16);
        s_acc[kc][r] = fmaf(s_acc[kc][r], scale_h, bf_);
      }

    // online softmax (per q-row across 16 lanes)
    float pf[4][4];
#pragma unroll
    for (int r = 0; r < 4; ++r) {
      float mx = fmaxf(fmaxf(s_acc[0][r], s_acc[1][r]),
                       fmaxf(s_acc[2][r], s_acc[3][r]));
      mx = fmaxf(mx, __shfl_xor(mx, 1));
      mx = fmaxf(mx, __shfl_xor(mx, 2));
      mx = fmaxf(mx, __shfl_xor(mx, 4));
      mx = fmaxf(mx, __shfl_xor(mx, 8));
      float m_new = fmaxf(m_run[r], mx);
      float alpha = __expf(m_run[r] - m_new);
      m_run[r] = m_new;
      float ps = 0.f;
#pragma unroll
      for (int kc = 0; kc < 4; ++kc) {
        float p = __expf(s_acc[kc][r] - m_new);
        pf[kc][r] = p;
        ps += p;
      }
      l_run[r] = l_run[r] * alpha + ps;
#pragma unroll
      for (int ds = 0; ds < 4; ++ds) acc_o[ds][r] *= alpha;
    }

    // P -> per-wave LDS (wave-local ordering via lgkmcnt; no barrier)
#pragma unroll
    for (int kc = 0; kc < 4; ++kc)
#pragma unroll
      for (int r = 0; r < 4; ++r) {
        int q = lg * 4 + r;
        pl[w][(q * 64 + kc * 16 + lr) ^ ((q & 7) << 3)] = cvt_bf16(pf[kc][r]);
      }

    // O += P @ V (B-frags: contiguous 16B loads from global V^T)
#pragma unroll
    for (int ka = 0; ka < 2; ++ka) {
      bf16x8 pa = *(const bf16x8*)&pl[w][(lr * 64 + ka * 32 + lg * 8) ^
                                         ((lr & 7) << 3)];
#pragma unroll
      for (int ds = 0; ds < 4; ++ds) {
        int d = ds * 16 + lr;
        bf16x8 bv = *(const bf16x8*)&vtg[vbase + (size_t)d * NN +
                                         ktg * 64 + ka * 32 + lg * 8];
        acc_o[ds] = __builtin_amdgcn_mfma_f32_16x16x32_bf16(pa, bv, acc_o[ds], 0, 0, 0);
      }
    }

    if (t + 1 < NT) {
#pragma unroll
      for (int r = 0; r < 4; ++r)
#pragma unroll
        for (int kc = 0; kc < 4; ++kc) bu[kc][r] = bu2[kc][r];
    }
  }

#pragma unroll
  for (int r = 0; r < 4; ++r) {
    l_run[r] += __shfl_xor(l_run[r], 1);
    l_run[r] += __shfl_xor(l_run[r], 2);
    l_run[r] += __shfl_xor(l_run[r], 4);
    l_run[r] += __shfl_xor(l_run[r], 8);
  }

  if (NSPLIT == 1) {
#pragma unroll
    for (int ds = 0; ds < 4; ++ds)
#pragma unroll
      for (int r = 0; r < 4; ++r) {
        int qg = qt * 64 + w * 16 + lg * 4 + r;
        attb[((size_t)b * NN + qg) * DD + h * DHH + ds * 16 + lr] =
            cvt_bf16(acc_o[ds][r] / l_run[r]);
      }
  } else {
#pragma unroll
    for (int r = 0; r < 4; ++r) {
      int qg = qt * 64 + w * 16 + lg * 4 + r;
      size_t idx = ((size_t)(sp * nb + b) * HH + h) * NN + qg;
      unsigned short* pr = part + idx * 68;
#pragma unroll
      for (int ds = 0; ds < 4; ++ds)
        pr[ds * 16 + lr] = cvt_bf16(acc_o[ds][r]);
      if (lr == 0) {
        *(float*)(pr + 64) = m_run[r];
        *(float*)(pr + 66) = l_run[r];
      }
    }
  }
}

// ---------------- combine 2 k-split partials -> att bf16 ----------------------
__global__ __launch_bounds__(256) void combine_kernel(
    const unsigned short* __restrict__ part, unsigned short* __restrict__ attb,
    int nb) {
  int tid = threadIdx.x;
  int w = tid >> 6, d = tid & 63;
  int row = blockIdx.x * 4 + w;
  int b = row >> 13, rem = row & 8191, h = rem >> 10, n = rem & (NN - 1);
  size_t i0 = ((size_t)b * HH + h) * NN + n;
  size_t i1 = i0 + (size_t)nb * HH * NN;
  const unsigned short* p0 = part + i0 * 68;
  const unsigned short* p1 = part + i1 * 68;
  float m0 = *(const float*)(p0 + 64), l0 = *(const float*)(p0 + 66);
  float m1 = *(const float*)(p1 + 64), l1 = *(const float*)(p1 + 66);
  float ms = fmaxf(m0, m1);
  float w0 = __expf(m0 - ms), w1 = __expf(m1 - ms);
  float a0 = __uint_as_float(((unsigned)p0[d]) << 16);
  float a1 = __uint_as_float(((unsigned)p1[d]) << 16);
  float o = (a0 * w0 + a1 * w1) / (l0 * w0 + l1 * w1);
  attb[((size_t)b * NN + n) * DD + h * DHH + d] = cvt_bf16(o);
}

// ---------------- launcher ----------------
extern "C" void kernel_launch(void* const* d_in, const int* in_sizes, int n_in,
                              void* d_out, int out_size, void* d_ws, size_t ws_size,
                              hipStream_t stream) {
  const float* x      = (const float*)d_in[0];
  const float* coords = (const float*)d_in[1];
  const float* Wq = (const float*)d_in[2];  const float* bq = (const float*)d_in[3];
  const float* Wk = (const float*)d_in[4];  const float* bk = (const float*)d_in[5];
  const float* Wv = (const float*)d_in[6];  const float* bv = (const float*)d_in[7];
  const float* Wo = (const float*)d_in[8];  const float* bo = (const float*)d_in[9];
  const float* logit_scale = (const float*)d_in[10];
  const float* W_pe = (const float*)d_in[11]; const float* b_pe = (const float*)d_in[12];
  const float* W_r1 = (const float*)d_in[13]; const float* b_r1 = (const float*)d_in[14];
  const float* W_r2 = (const float*)d_in[15]; const float* b_r2 = (const float*)d_in[16];
  const float* g_peq = (const float*)d_in[17]; const float* bt_peq = (const float*)d_in[18];
  const float* g_pek = (const float*)d_in[19]; const float* bt_pek = (const float*)d_in[20];
  const float* g2 = (const float*)d_in[21]; const float* bt2 = (const float*)d_in[22];
  const float* g3 = (const float*)d_in[23]; const float* bt3 = (const float*)d_in[24];
  const float* W_ff1 = (const float*)d_in[25];
  const float* W_ff2 = (const float*)d_in[26];
  float* out = (float*)d_out;

  const size_t T = (size_t)BB * NN;
  char* wsb = (char*)d_ws;
  const size_t U = 4u * 1024u * 1024u;

  unsigned short* wt_all = (unsigned short*)(wsb + 0 * U);   // [0,2U)
  unsigned short* WoT   = wt_all + 786432;
  unsigned short* Wff1T = wt_all + 1048576;
  unsigned short* Wff2T = wt_all + 2097152;
  unsigned short* q_lnb = (unsigned short*)(wsb + 2 * U);
  unsigned short* k_lnb = (unsigned short*)(wsb + 3 * U);
  unsigned short* x_bf  = (unsigned short*)(wsb + 4 * U);
  unsigned short* q_bf  = (unsigned short*)(wsb + 5 * U);
  unsigned short* k_bf  = (unsigned short*)(wsb + 6 * U);
  unsigned short* v_bf  = (unsigned short*)(wsb + 7 * U);    // V^T [B,H,64,N]
  unsigned short* att_bf = (unsigned short*)(wsb + 8 * U);
  float* proj = (float*)(wsb + 9 * U);                        // [9U,11U)
  float* x1   = (float*)(wsb + 11 * U);                       // [11U,13U)
  unsigned short* x1_bf = (unsigned short*)(wsb + 13 * U);    // [13U,14U)
  unsigned short* hid_bf = (unsigned short*)(wsb + 2 * U);    // [2U,6U)
  float* mlp  = (float*)(wsb + 9 * U);
  unsigned short* part_ws = (unsigned short*)(wsb + 2 * U);   // 8.5 MiB
  unsigned short* bias_ws = (unsigned short*)(wsb + 9 * U);   // 64 MiB [9U,25U)

  const int full_path = (ws_size >= 25 * U) ? 1 : 0;

  wconv_kernel<<<dim3(768), dim3(256), 0, stream>>>(
      Wq, Wk, Wv, Wo, W_ff1, W_ff2, wt_all);

  pe_ln_kernel<<<dim3(T), dim3(512), 0, stream>>>(
      x, coords, W_pe, b_pe, g_peq, bt_peq, g_pek, bt_pek, q_lnb, k_lnb, x_bf);

  qkv_gemm_kernel<<<dim3(DD / 128, T / 128, 3), dim3(256), 0, stream>>>(
      q_lnb, k_lnb, x_bf, wt_all, bq, bk, bv, q_bf, k_bf, v_bf);

  if (full_path) {
    bias_kernel<<<dim3(NN / 32, NN / 64, BB), dim3(256), 0, stream>>>(
        coords, W_r1, b_r1, W_r2, b_r2, bias_ws);
    attn_wave_kernel<2><<<dim3(NN / 64, HH, 2 * BB), dim3(256), 0, stream>>>(
        q_bf, k_bf, v_bf, bias_ws, logit_scale, nullptr, part_ws, BB);
    combine_kernel<<<dim3(BB * HH * NN / 4), dim3(256), 0, stream>>>(
        part_ws, att_bf, BB);
  } else {
    for (int b = 0; b < BB; ++b) {
      bias_kernel<<<dim3(NN / 32, NN / 64, 1), dim3(256), 0, stream>>>(
          coords + (size_t)b * NN * 2, W_r1, b_r1, W_r2, b_r2, bias_ws);
      attn_wave_kernel<1><<<dim3(NN / 64, HH, 1), dim3(256), 0, stream>>>(
          q_bf + (size_t)b * HH * NN * DHH, k_bf + (size_t)b * HH * NN * DHH,
          v_bf + (size_t)b * HH * DHH * NN, bias_ws, logit_scale,
          att_bf + (size_t)b * NN * DD, nullptr, 1);
    }
  }

  mgemm_kernel<0, 0><<<dim3(DD / 128, T / 128), dim3(256), 0, stream>>>(
      att_bf, WoT, bo, proj, (int)T, DD, DD);

  add_ln_kernel<<<dim3(T), dim3(512), 0, stream>>>(x, proj, g2, bt2, x1, x1_bf);

  mgemm_kernel<1, 1><<<dim3(FFF / 128, T / 128), dim3(256), 0, stream>>>(
      x1_bf, Wff1T, nullptr, hid_bf, (int)T, FFF, DD);
  mgemm_kernel<1, 0><<<dim3(DD / 128, T / 128), dim3(256), 0, stream>>>(
      hid_bf, Wff2T, nullptr, mlp, (int)T, DD, FFF);

  add_ln_kernel<<<dim3(T), dim3(512), 0, stream>>>(x1, mlp, g3, bt3, out, nullptr);
}

// Round 7
// 195.356 us; speedup vs baseline: 23.0915x; 1.0139x over previous
//
#include <hip/hip_runtime.h>

#define BB 4
#define NN 1024
#define DD 512
#define HH 8
#define DHH 64
#define FFF 2048

typedef __attribute__((ext_vector_type(8))) short bf16x8;
typedef __attribute__((ext_vector_type(4))) float f32x4;

__device__ inline float wave_sum(float v) {
#pragma unroll
  for (int off = 32; off; off >>= 1) v += __shfl_xor(v, off);
  return v;
}

__device__ inline unsigned short cvt_bf16(float f) {
  union { float f; unsigned u; } x;
  x.f = f;
  unsigned r = x.u + 0x7FFFu + ((x.u >> 16) & 1u);
  return (unsigned short)(r >> 16);
}

__device__ __forceinline__ void gl_lds16(const void* g, void* l) {
  __builtin_amdgcn_global_load_lds(
      (__attribute__((address_space(1))) void*)(g),
      (__attribute__((address_space(3))) void*)(l), 16, 0, 0);
}

// ---------------- weight transpose + bf16 convert (all 6 weights, 1 launch) ----
__global__ __launch_bounds__(256) void wconv_kernel(
    const float* __restrict__ W0, const float* __restrict__ W1,
    const float* __restrict__ W2, const float* __restrict__ W3,
    const float* __restrict__ W4, const float* __restrict__ W5,
    unsigned short* __restrict__ out) {
  int bidx = blockIdx.x;
  const float* W; unsigned short* Wt; int K, N, local;
  if (bidx < 256) {
    int sel = bidx >> 6; local = bidx & 63;
    W = sel == 0 ? W0 : sel == 1 ? W1 : sel == 2 ? W2 : W3;
    K = 512; N = 512; Wt = out + (size_t)sel * 262144;
  } else if (bidx < 512) {
    local = bidx - 256; W = W4; K = 512; N = 2048; Wt = out + 1048576;
  } else {
    local = bidx - 512; W = W5; K = 2048; N = 512; Wt = out + 2097152;
  }
  int ntn = N >> 6;
  int tn = (local & (ntn - 1)) << 6, tk = (local / ntn) << 6;
  __shared__ float tile[64][65];
  int tid = threadIdx.x;
#pragma unroll
  for (int i = 0; i < 16; ++i) {
    int e = tid + i * 256, kk = e >> 6, nn = e & 63;
    tile[kk][nn] = W[(size_t)(tk + kk) * N + tn + nn];
  }
  __syncthreads();
#pragma unroll
  for (int i = 0; i < 16; ++i) {
    int e = tid + i * 256, nn = e >> 6, kk = e & 63;
    Wt[(size_t)(tn + nn) * K + tk + kk] = cvt_bf16(tile[kk][nn]);
  }
}

// ------- RPE bias materialization, tile-blocked: [b,h,qt,kt][64*64] bf16 -------
__global__ __launch_bounds__(256) void bias_kernel(
    const float* __restrict__ coords,
    const float* __restrict__ W_r1, const float* __restrict__ b_r1,
    const float* __restrict__ W_r2, const float* __restrict__ b_r2,
    unsigned short* __restrict__ bias_out) {
  int kt = blockIdx.x, qt = blockIdx.y, b = blockIdx.z;
  int tid = threadIdx.x;
  int qL = tid >> 2;
  int q = qt * 64 + qL;
  int k0 = kt * 32 + (tid & 3) * 8;
  float cq0 = coords[((size_t)b * NN + q) * 2 + 0];
  float cq1 = coords[((size_t)b * NN + q) * 2 + 1];
  float Aq[16];
#pragma unroll
  for (int l = 0; l < 16; ++l)
    Aq[l] = fmaf(cq0, W_r1[l], fmaf(cq1, W_r1[16 + l], b_r1[l]));
  float ck0[8], ck1[8];
#pragma unroll
  for (int kk = 0; kk < 8; ++kk) {
    ck0[kk] = coords[((size_t)b * NN + k0 + kk) * 2 + 0];
    ck1[kk] = coords[((size_t)b * NN + k0 + kk) * 2 + 1];
  }
  float acc[8][8];
#pragma unroll
  for (int kk = 0; kk < 8; ++kk)
#pragma unroll
    for (int h = 0; h < 8; ++h) acc[kk][h] = b_r2[h];
#pragma unroll
  for (int l = 0; l < 16; ++l) {
    float w1a = W_r1[l], w1b = W_r1[16 + l];
#pragma unroll
    for (int kk = 0; kk < 8; ++kk) {
      float hv = Aq[l] - fmaf(ck0[kk], w1a, ck1[kk] * w1b);
      hv = fmaxf(hv, 0.f);
#pragma unroll
      for (int h = 0; h < 8; ++h)
        acc[kk][h] = fmaf(hv, W_r2[l * HH + h], acc[kk][h]);
    }
  }
  int elem = qL * 64 + (kt & 1) * 32 + (tid & 3) * 8;
#pragma unroll
  for (int h = 0; h < 8; ++h) {
    bf16x8 ov;
#pragma unroll
    for (int kk = 0; kk < 8; ++kk) ov[kk] = (short)cvt_bf16(acc[kk][h]);
    size_t tile = (((size_t)b * HH + h) * 16 + qt) * 16 + (kt >> 1);
    *(bf16x8*)&bias_out[tile * 4096 + elem] = ov;
  }
}

// ---------------- PE add + dual LayerNorm -> bf16, plus bf16 copy of x --------
__global__ __launch_bounds__(512) void pe_ln_kernel(
    const float* __restrict__ x, const float* __restrict__ coords,
    const float* __restrict__ W_pe, const float* __restrict__ b_pe,
    const float* __restrict__ g_q, const float* __restrict__ bt_q,
    const float* __restrict__ g_k, const float* __restrict__ bt_k,
    unsigned short* __restrict__ q_lnb, unsigned short* __restrict__ k_lnb,
    unsigned short* __restrict__ x_bf) {
  int row = blockIdx.x;
  int tid = threadIdx.x;
  float c0 = coords[(size_t)row * 2 + 0];
  float c1 = coords[(size_t)row * 2 + 1];
  size_t idx = (size_t)row * DD + tid;
  float xv = x[idx];
  x_bf[idx] = cvt_bf16(xv);
  float val = xv + c0 * W_pe[tid] + c1 * W_pe[DD + tid] + b_pe[tid];

  __shared__ float ws[8], ws2[8];
  float s = wave_sum(val);
  if ((tid & 63) == 0) ws[tid >> 6] = s;
  __syncthreads();
  float mean = 0.f;
#pragma unroll
  for (int w = 0; w < 8; ++w) mean += ws[w];
  mean *= (1.f / DD);
  float dv = val - mean;
  float s2 = wave_sum(dv * dv);
  if ((tid & 63) == 0) ws2[tid >> 6] = s2;
  __syncthreads();
  float var = 0.f;
#pragma unroll
  for (int w = 0; w < 8; ++w) var += ws2[w];
  var *= (1.f / DD);
  float rstd = rsqrtf(var + 1e-5f);
  q_lnb[idx] = cvt_bf16(dv * rstd * g_q[tid] + bt_q[tid]);
  k_lnb[idx] = cvt_bf16(dv * rstd * g_k[tid] + bt_k[tid]);
}

// ---------------- residual add + LayerNorm (f32 out + optional bf16 out) ------
__global__ __launch_bounds__(512) void add_ln_kernel(
    const float* __restrict__ a, const float* __restrict__ r,
    const float* __restrict__ g, const float* __restrict__ bt,
    float* __restrict__ out, unsigned short* __restrict__ out_bf) {
  int row = blockIdx.x;
  int tid = threadIdx.x;
  size_t idx = (size_t)row * DD + tid;
  float val = a[idx] + r[idx];
  __shared__ float ws[8], ws2[8];
  float s = wave_sum(val);
  if ((tid & 63) == 0) ws[tid >> 6] = s;
  __syncthreads();
  float mean = 0.f;
#pragma unroll
  for (int w = 0; w < 8; ++w) mean += ws[w];
  mean *= (1.f / DD);
  float dv = val - mean;
  float s2 = wave_sum(dv * dv);
  if ((tid & 63) == 0) ws2[tid >> 6] = s2;
  __syncthreads();
  float var = 0.f;
#pragma unroll
  for (int w = 0; w < 8; ++w) var += ws2[w];
  var *= (1.f / DD);
  float rstd = rsqrtf(var + 1e-5f);
  float o = dv * rstd * g[tid] + bt[tid];
  out[idx] = o;
  if (out_bf) out_bf[idx] = cvt_bf16(o);
}

// ---------------- bf16 MFMA GEMM: C = act(A[M,K] @ BT[N,K]^T + bias) ----------
template <int ACT, int EPI>
__global__ __launch_bounds__(256) void mgemm_kernel(
    const unsigned short* __restrict__ A, const unsigned short* __restrict__ BT,
    const float* __restrict__ bias, void* __restrict__ C,
    int M, int Nc, int K) {
  __shared__ unsigned short lds[4][8192];
  int tid = threadIdx.x;
  int w = tid >> 6, lane = tid & 63, lg = lane >> 4, lr = lane & 15;
  int bm = blockIdx.y * 128, bn = blockIdx.x * 128;
  int wr = w >> 1, wc = w & 1;

  int segl = lane >> 3;
  int cb = (lane & 7) << 4;

  f32x4 zf = {0.f, 0.f, 0.f, 0.f};
  f32x4 acc[4][4];
#pragma unroll
  for (int mi = 0; mi < 4; ++mi)
#pragma unroll
    for (int ni = 0; ni < 4; ++ni) acc[mi][ni] = zf;

  int nt = K >> 6;

  auto STAGE = [&](int buf, int t) {
    int k0 = t << 6;
#pragma unroll
    for (int i = 0; i < 4; ++i) {
      int seg = w * 4 + i;
      int r = (seg << 3) + segl;
      int csw = cb ^ ((r & 7) << 4);
      const char* ga = (const char*)A + (((size_t)(bm + r) * K + k0) << 1) + csw;
      gl_lds16(ga, &lds[buf * 2][seg << 9]);
      const char* gb = (const char*)BT + (((size_t)(bn + r) * K + k0) << 1) + csw;
      gl_lds16(gb, &lds[buf * 2 + 1][seg << 9]);
    }
  };

  auto COMPUTE = [&](int buf) {
    const unsigned short* As = lds[buf * 2];
    const unsigned short* Bs = lds[buf * 2 + 1];
    bf16x8 af[2][4], bfr[2][4];
#pragma unroll
    for (int kh = 0; kh < 2; ++kh)
#pragma unroll
      for (int mi = 0; mi < 4; ++mi) {
        int r = wr * 64 + mi * 16 + lr;
        int e = (r << 6) + (kh << 5) + (lg << 3);
        af[kh][mi] = *(const bf16x8*)&As[e ^ ((r & 7) << 3)];
        int rb = wc * 64 + mi * 16 + lr;
        int eb = (rb << 6) + (kh << 5) + (lg << 3);
        bfr[kh][mi] = *(const bf16x8*)&Bs[eb ^ ((rb & 7) << 3)];
      }
#pragma unroll
    for (int kh = 0; kh < 2; ++kh)
#pragma unroll
      for (int mi = 0; mi < 4; ++mi)
#pragma unroll
        for (int ni = 0; ni < 4; ++ni)
          acc[mi][ni] = __builtin_amdgcn_mfma_f32_16x16x32_bf16(
              af[kh][mi], bfr[kh][ni], acc[mi][ni], 0, 0, 0);
  };

  STAGE(0, 0);
  __syncthreads();
  for (int t = 0; t < nt; ++t) {
    if (t + 1 < nt) STAGE((t + 1) & 1, t + 1);
    COMPUTE(t & 1);
    __syncthreads();
  }

#pragma unroll
  for (int ni = 0; ni < 4; ++ni) {
    int col = bn + wc * 64 + ni * 16 + lr;
    float bv = bias ? bias[col] : 0.f;
#pragma unroll
    for (int mi = 0; mi < 4; ++mi) {
#pragma unroll
      for (int j = 0; j < 4; ++j) {
        int row = bm + wr * 64 + mi * 16 + lg * 4 + j;
        float v = acc[mi][ni][j] + bv;
        if (ACT == 1) v = v > 0.f ? v : 0.2f * v;
        if (EPI == 1)
          ((unsigned short*)C)[(size_t)row * Nc + col] = cvt_bf16(v);
        else
          ((float*)C)[(size_t)row * Nc + col] = v;
      }
    }
  }
}

// ---------------- fused QKV GEMM (z: 0=q norm, 1=k norm, 2=v -> V^T) ----------
__global__ __launch_bounds__(256) void qkv_gemm_kernel(
    const unsigned short* __restrict__ q_lnb,
    const unsigned short* __restrict__ k_lnb,
    const unsigned short* __restrict__ x_bf,
    const unsigned short* __restrict__ wt,
    const float* __restrict__ bq, const float* __restrict__ bk,
    const float* __restrict__ bv_,
    unsigned short* __restrict__ q_bf, unsigned short* __restrict__ k_bf,
    unsigned short* __restrict__ vt_g) {
  int z = blockIdx.z;
  const unsigned short* A = z == 0 ? q_lnb : z == 1 ? k_lnb : x_bf;
  const unsigned short* BT = wt + (size_t)z * 262144;
  const float* bias = z == 0 ? bq : z == 1 ? bk : bv_;

  __shared__ unsigned short lds[4][8192];
  int tid = threadIdx.x;
  int w = tid >> 6, lane = tid & 63, lg = lane >> 4, lr = lane & 15;
  int bm = blockIdx.y * 128, bn = blockIdx.x * 128;
  int wr = w >> 1, wc = w & 1;
  int segl = lane >> 3;
  int cb = (lane & 7) << 4;

  f32x4 zf = {0.f, 0.f, 0.f, 0.f};
  f32x4 acc[4][4];
#pragma unroll
  for (int mi = 0; mi < 4; ++mi)
#pragma unroll
    for (int ni = 0; ni < 4; ++ni) acc[mi][ni] = zf;

  auto STAGE = [&](int buf, int t) {
    int k0 = t << 6;
#pragma unroll
    for (int i = 0; i < 4; ++i) {
      int seg = w * 4 + i;
      int r = (seg << 3) + segl;
      int csw = cb ^ ((r & 7) << 4);
      const char* ga = (const char*)A + (((size_t)(bm + r) * DD + k0) << 1) + csw;
      gl_lds16(ga, &lds[buf * 2][seg << 9]);
      const char* gb = (const char*)BT + (((size_t)(bn + r) * DD + k0) << 1) + csw;
      gl_lds16(gb, &lds[buf * 2 + 1][seg << 9]);
    }
  };
  auto COMPUTE = [&](int buf) {
    const unsigned short* As = lds[buf * 2];
    const unsigned short* Bs = lds[buf * 2 + 1];
    bf16x8 af[2][4], bfr[2][4];
#pragma unroll
    for (int kh = 0; kh < 2; ++kh)
#pragma unroll
      for (int mi = 0; mi < 4; ++mi) {
        int r = wr * 64 + mi * 16 + lr;
        int e = (r << 6) + (kh << 5) + (lg << 3);
        af[kh][mi] = *(const bf16x8*)&As[e ^ ((r & 7) << 3)];
        int rb = wc * 64 + mi * 16 + lr;
        int eb = (rb << 6) + (kh << 5) + (lg << 3);
        bfr[kh][mi] = *(const bf16x8*)&Bs[eb ^ ((rb & 7) << 3)];
      }
#pragma unroll
    for (int kh = 0; kh < 2; ++kh)
#pragma unroll
      for (int mi = 0; mi < 4; ++mi)
#pragma unroll
        for (int ni = 0; ni < 4; ++ni)
          acc[mi][ni] = __builtin_amdgcn_mfma_f32_16x16x32_bf16(
              af[kh][mi], bfr[kh][ni], acc[mi][ni], 0, 0, 0);
  };

  STAGE(0, 0);
  __syncthreads();
  for (int t = 0; t < 8; ++t) {
    if (t + 1 < 8) STAGE((t + 1) & 1, t + 1);
    COMPUTE(t & 1);
    __syncthreads();
  }

  int h = (bn >> 6) + wc;
  float bvf[4];
#pragma unroll
  for (int ni = 0; ni < 4; ++ni) bvf[ni] = bias[bn + wc * 64 + ni * 16 + lr];
#pragma unroll
  for (int mi = 0; mi < 4; ++mi) {
#pragma unroll
    for (int j = 0; j < 4; ++j) {
      float vals[4]; float ss = 0.f;
#pragma unroll
      for (int ni = 0; ni < 4; ++ni) {
        float v = acc[mi][ni][j] + bvf[ni];
        vals[ni] = v;
        ss = fmaf(v, v, ss);
      }
      int row = bm + wr * 64 + mi * 16 + lg * 4 + j;
      int b_ = row >> 10, n_ = row & (NN - 1);
      if (z <= 1) {
        ss += __shfl_xor(ss, 1);
        ss += __shfl_xor(ss, 2);
        ss += __shfl_xor(ss, 4);
        ss += __shfl_xor(ss, 8);
        float rn = 1.f / fmaxf(sqrtf(ss), 1e-12f);
        unsigned short* ob = (z == 0 ? q_bf : k_bf) +
                             (((size_t)b_ * HH + h) * NN + n_) * DHH;
#pragma unroll
        for (int ni = 0; ni < 4; ++ni)
          ob[ni * 16 + lr] = cvt_bf16(vals[ni] * rn);
      } else {
#pragma unroll
        for (int ni = 0; ni < 4; ++ni)
          vt_g[(((size_t)b_ * HH + h) * DHH + ni * 16 + lr) * NN + n_] =
              cvt_bf16(vals[ni]);
      }
    }
  }
}

// -------- barrier-free MFMA flash attention, tile-blocked bias via LDS --------
// bias_t: [b,h,qt,kt][64*64] bf16 tiles. Per-wave dbuf LDS staging, no barriers.
template <int NSPLIT>
__global__ __launch_bounds__(256) void attn_wave_kernel(
    const unsigned short* __restrict__ qb, const unsigned short* __restrict__ kb,
    const unsigned short* __restrict__ vtg,
    const unsigned short* __restrict__ bias_t,
    const float* __restrict__ logit_scale,
    unsigned short* __restrict__ attb,
    unsigned short* __restrict__ part, int nb) {
  int qt = blockIdx.x, h = blockIdx.y;
  int b = blockIdx.z % nb, sp = blockIdx.z / nb;
  int tid = threadIdx.x;
  int w = tid >> 6, lane = tid & 63;
  int lg = lane >> 4, lr = lane & 15;

  __shared__ unsigned short bl[4][2][1024];  // per-wave bias slice, swizzled
  __shared__ unsigned short pl[4][1024];     // per-wave P, swizzled

  const size_t bh = ((size_t)b * HH + h) * NN;
  const size_t vbase = ((size_t)b * HH + h) * DHH * NN;
  const int NT = (NN / 64) / NSPLIT;
  const int kt0 = sp * NT;
  // wave's slice of the blocked bias tile: rows [w*16, w*16+16)
  const unsigned short* bsrc0 =
      bias_t + ((((size_t)b * HH + h) * 16 + qt) * 16 + kt0) * 4096 +
      w * 1024 + lane * 8;

  // swizzled ds_write chunk targets (chunk = 16B = 8 elems)
  int rr0 = lane >> 3, rr1 = 8 + (lane >> 3);
  int d0 = (rr0 * 8 + ((lane & 7) ^ (rr0 & 7))) * 8;
  int d1 = (rr1 * 8 + ((lane & 7) ^ (rr1 & 7))) * 8;

  int q_glob = qt * 64 + w * 16 + lr;
  bf16x8 aq0 = *(const bf16x8*)&qb[(bh + q_glob) * DHH + lg * 8];
  bf16x8 aq1 = *(const bf16x8*)&qb[(bh + q_glob) * DHH + 32 + lg * 8];

  float scale_h = __expf(fminf(logit_scale[h], 4.605170185988091f));

  float m_run[4] = {-1e30f, -1e30f, -1e30f, -1e30f};
  float l_run[4] = {0.f, 0.f, 0.f, 0.f};
  f32x4 zf = {0.f, 0.f, 0.f, 0.f};
  f32x4 acc_o[4] = {zf, zf, zf, zf};

  // stage bias tile 0 (coalesced 16B loads -> swizzled per-wave LDS)
  {
    bf16x8 br0 = *(const bf16x8*)bsrc0;
    bf16x8 br1 = *(const bf16x8*)(bsrc0 + 512);
    *(bf16x8*)&bl[w][0][d0] = br0;
    *(bf16x8*)&bl[w][0][d1] = br1;
  }

  for (int t = 0; t < NT; ++t) {
    int cur = t & 1;
    int ktg = kt0 + t;

    // issue next bias tile loads early (hide under QK/softmax/PV)
    bf16x8 nb0, nb1;
    if (t + 1 < NT) {
      const unsigned short* bs = bsrc0 + (size_t)(t + 1) * 4096;
      nb0 = *(const bf16x8*)bs;
      nb1 = *(const bf16x8*)(bs + 512);
    }

    // QK^T
    f32x4 s_acc[4];
#pragma unroll
    for (int kc = 0; kc < 4; ++kc) {
      const unsigned short* krow =
          &kb[(bh + ktg * 64 + kc * 16 + lr) * DHH + lg * 8];
      bf16x8 bk0 = *(const bf16x8*)krow;
      bf16x8 bk1 = *(const bf16x8*)(krow + 32);
      s_acc[kc] = __builtin_amdgcn_mfma_f32_16x16x32_bf16(aq0, bk0, zf, 0, 0, 0);
      s_acc[kc] = __builtin_amdgcn_mfma_f32_16x16x32_bf16(aq1, bk1, s_acc[kc], 0, 0, 0);
    }

    // scale + bias from per-wave LDS (swizzled u16 reads)
#pragma unroll
    for (int kc = 0; kc < 4; ++kc)
#pragma unroll
      for (int r = 0; r < 4; ++r) {
        int rr = lg * 4 + r;
        unsigned short ub =
            bl[w][cur][(rr * 64 + kc * 16 + lr) ^ ((rr & 7) << 3)];
        float bf_ = __uint_as_float(((unsigned)ub) << 16);
        s_acc[kc][r] = fmaf(s_acc[kc][r], scale_h, bf_);
      }

    // online softmax (per q-row across 16 lanes)
    float pf[4][4];
#pragma unroll
    for (int r = 0; r < 4; ++r) {
      float mx = fmaxf(fmaxf(s_acc[0][r], s_acc[1][r]),
                       fmaxf(s_acc[2][r], s_acc[3][r]));
      mx = fmaxf(mx, __shfl_xor(mx, 1));
      mx = fmaxf(mx, __shfl_xor(mx, 2));
      mx = fmaxf(mx, __shfl_xor(mx, 4));
      mx = fmaxf(mx, __shfl_xor(mx, 8));
      float m_new = fmaxf(m_run[r], mx);
      float alpha = __expf(m_run[r] - m_new);
      m_run[r] = m_new;
      float ps = 0.f;
#pragma unroll
      for (int kc = 0; kc < 4; ++kc) {
        float p = __expf(s_acc[kc][r] - m_new);
        pf[kc][r] = p;
        ps += p;
      }
      l_run[r] = l_run[r] * alpha + ps;
#pragma unroll
      for (int ds = 0; ds < 4; ++ds) acc_o[ds][r] *= alpha;
    }

    // P -> per-wave LDS (wave-local, lgkmcnt ordering only)
#pragma unroll
    for (int kc = 0; kc < 4; ++kc)
#pragma unroll
      for (int r = 0; r < 4; ++r) {
        int q = lg * 4 + r;
        pl[w][(q * 64 + kc * 16 + lr) ^ ((q & 7) << 3)] = cvt_bf16(pf[kc][r]);
      }

    // O += P @ V (contiguous 16B loads from global V^T)
#pragma unroll
    for (int ka = 0; ka < 2; ++ka) {
      bf16x8 pa = *(const bf16x8*)&pl[w][(lr * 64 + ka * 32 + lg * 8) ^
                                         ((lr & 7) << 3)];
#pragma unroll
      for (int ds = 0; ds < 4; ++ds) {
        int d = ds * 16 + lr;
        bf16x8 bv = *(const bf16x8*)&vtg[vbase + (size_t)d * NN +
                                         ktg * 64 + ka * 32 + lg * 8];
        acc_o[ds] = __builtin_amdgcn_mfma_f32_16x16x32_bf16(pa, bv, acc_o[ds], 0, 0, 0);
      }
    }

    // write next bias tile into the other buffer (loads have had time to land)
    if (t + 1 < NT) {
      *(bf16x8*)&bl[w][cur ^ 1][d0] = nb0;
      *(bf16x8*)&bl[w][cur ^ 1][d1] = nb1;
    }
  }

#pragma unroll
  for (int r = 0; r < 4; ++r) {
    l_run[r] += __shfl_xor(l_run[r], 1);
    l_run[r] += __shfl_xor(l_run[r], 2);
    l_run[r] += __shfl_xor(l_run[r], 4);
    l_run[r] += __shfl_xor(l_run[r], 8);
  }

  if (NSPLIT == 1) {
#pragma unroll
    for (int ds = 0; ds < 4; ++ds)
#pragma unroll
      for (int r = 0; r < 4; ++r) {
        int qg = qt * 64 + w * 16 + lg * 4 + r;
        attb[((size_t)b * NN + qg) * DD + h * DHH + ds * 16 + lr] =
            cvt_bf16(acc_o[ds][r] / l_run[r]);
      }
  } else {
#pragma unroll
    for (int r = 0; r < 4; ++r) {
      int qg = qt * 64 + w * 16 + lg * 4 + r;
      size_t idx = ((size_t)(sp * nb + b) * HH + h) * NN + qg;
      unsigned short* pr = part + idx * 68;
#pragma unroll
      for (int ds = 0; ds < 4; ++ds)
        pr[ds * 16 + lr] = cvt_bf16(acc_o[ds][r]);
      if (lr == 0) {
        *(float*)(pr + 64) = m_run[r];
        *(float*)(pr + 66) = l_run[r];
      }
    }
  }
}

// ---------------- combine 2 k-split partials -> att bf16 ----------------------
__global__ __launch_bounds__(256) void combine_kernel(
    const unsigned short* __restrict__ part, unsigned short* __restrict__ attb,
    int nb) {
  int tid = threadIdx.x;
  int w = tid >> 6, d = tid & 63;
  int row = blockIdx.x * 4 + w;
  int b = row >> 13, rem = row & 8191, h = rem >> 10, n = rem & (NN - 1);
  size_t i0 = ((size_t)b * HH + h) * NN + n;
  size_t i1 = i0 + (size_t)nb * HH * NN;
  const unsigned short* p0 = part + i0 * 68;
  const unsigned short* p1 = part + i1 * 68;
  float m0 = *(const float*)(p0 + 64), l0 = *(const float*)(p0 + 66);
  float m1 = *(const float*)(p1 + 64), l1 = *(const float*)(p1 + 66);
  float ms = fmaxf(m0, m1);
  float w0 = __expf(m0 - ms), w1 = __expf(m1 - ms);
  float a0 = __uint_as_float(((unsigned)p0[d]) << 16);
  float a1 = __uint_as_float(((unsigned)p1[d]) << 16);
  float o = (a0 * w0 + a1 * w1) / (l0 * w0 + l1 * w1);
  attb[((size_t)b * NN + n) * DD + h * DHH + d] = cvt_bf16(o);
}

// ---------------- launcher ----------------
extern "C" void kernel_launch(void* const* d_in, const int* in_sizes, int n_in,
                              void* d_out, int out_size, void* d_ws, size_t ws_size,
                              hipStream_t stream) {
  const float* x      = (const float*)d_in[0];
  const float* coords = (const float*)d_in[1];
  const float* Wq = (const float*)d_in[2];  const float* bq = (const float*)d_in[3];
  const float* Wk = (const float*)d_in[4];  const float* bk = (const float*)d_in[5];
  const float* Wv = (const float*)d_in[6];  const float* bv = (const float*)d_in[7];
  const float* Wo = (const float*)d_in[8];  const float* bo = (const float*)d_in[9];
  const float* logit_scale = (const float*)d_in[10];
  const float* W_pe = (const float*)d_in[11]; const float* b_pe = (const float*)d_in[12];
  const float* W_r1 = (const float*)d_in[13]; const float* b_r1 = (const float*)d_in[14];
  const float* W_r2 = (const float*)d_in[15]; const float* b_r2 = (const float*)d_in[16];
  const float* g_peq = (const float*)d_in[17]; const float* bt_peq = (const float*)d_in[18];
  const float* g_pek = (const float*)d_in[19]; const float* bt_pek = (const float*)d_in[20];
  const float* g2 = (const float*)d_in[21]; const float* bt2 = (const float*)d_in[22];
  const float* g3 = (const float*)d_in[23]; const float* bt3 = (const float*)d_in[24];
  const float* W_ff1 = (const float*)d_in[25];
  const float* W_ff2 = (const float*)d_in[26];
  float* out = (float*)d_out;

  const size_t T = (size_t)BB * NN;
  char* wsb = (char*)d_ws;
  const size_t U = 4u * 1024u * 1024u;

  unsigned short* wt_all = (unsigned short*)(wsb + 0 * U);   // [0,2U)
  unsigned short* WoT   = wt_all + 786432;
  unsigned short* Wff1T = wt_all + 1048576;
  unsigned short* Wff2T = wt_all + 2097152;
  unsigned short* q_lnb = (unsigned short*)(wsb + 2 * U);
  unsigned short* k_lnb = (unsigned short*)(wsb + 3 * U);
  unsigned short* x_bf  = (unsigned short*)(wsb + 4 * U);
  unsigned short* q_bf  = (unsigned short*)(wsb + 5 * U);
  unsigned short* k_bf  = (unsigned short*)(wsb + 6 * U);
  unsigned short* v_bf  = (unsigned short*)(wsb + 7 * U);    // V^T [B,H,64,N]
  unsigned short* att_bf = (unsigned short*)(wsb + 8 * U);
  float* proj = (float*)(wsb + 9 * U);                        // [9U,11U)
  float* x1   = (float*)(wsb + 11 * U);                       // [11U,13U)
  unsigned short* x1_bf = (unsigned short*)(wsb + 13 * U);    // [13U,14U)
  unsigned short* hid_bf = (unsigned short*)(wsb + 2 * U);    // [2U,6U)
  float* mlp  = (float*)(wsb + 9 * U);
  unsigned short* part_ws = (unsigned short*)(wsb + 2 * U);   // 8.5 MiB
  unsigned short* bias_ws = (unsigned short*)(wsb + 9 * U);   // 64 MiB [9U,25U)

  const int full_path = (ws_size >= 25 * U) ? 1 : 0;

  wconv_kernel<<<dim3(768), dim3(256), 0, stream>>>(
      Wq, Wk, Wv, Wo, W_ff1, W_ff2, wt_all);

  pe_ln_kernel<<<dim3(T), dim3(512), 0, stream>>>(
      x, coords, W_pe, b_pe, g_peq, bt_peq, g_pek, bt_pek, q_lnb, k_lnb, x_bf);

  qkv_gemm_kernel<<<dim3(DD / 128, T / 128, 3), dim3(256), 0, stream>>>(
      q_lnb, k_lnb, x_bf, wt_all, bq, bk, bv, q_bf, k_bf, v_bf);

  if (full_path) {
    bias_kernel<<<dim3(NN / 32, NN / 64, BB), dim3(256), 0, stream>>>(
        coords, W_r1, b_r1, W_r2, b_r2, bias_ws);
    attn_wave_kernel<2><<<dim3(NN / 64, HH, 2 * BB), dim3(256), 0, stream>>>(
        q_bf, k_bf, v_bf, bias_ws, logit_scale, nullptr, part_ws, BB);
    combine_kernel<<<dim3(BB * HH * NN / 4), dim3(256), 0, stream>>>(
        part_ws, att_bf, BB);
  } else {
    for (int b = 0; b < BB; ++b) {
      bias_kernel<<<dim3(NN / 32, NN / 64, 1), dim3(256), 0, stream>>>(
          coords + (size_t)b * NN * 2, W_r1, b_r1, W_r2, b_r2, bias_ws);
      attn_wave_kernel<1><<<dim3(NN / 64, HH, 1), dim3(256), 0, stream>>>(
          q_bf + (size_t)b * HH * NN * DHH, k_bf + (size_t)b * HH * NN * DHH,
          v_bf + (size_t)b * HH * DHH * NN, bias_ws, logit_scale,
          att_bf + (size_t)b * NN * DD, nullptr, 1);
    }
  }

  mgemm_kernel<0, 0><<<dim3(DD / 128, T / 128), dim3(256), 0, stream>>>(
      att_bf, WoT, bo, proj, (int)T, DD, DD);

  add_ln_kernel<<<dim3(T), dim3(512), 0, stream>>>(x, proj, g2, bt2, x1, x1_bf);

  mgemm_kernel<1, 1><<<dim3(FFF / 128, T / 128), dim3(256), 0, stream>>>(
      x1_bf, Wff1T, nullptr, hid_bf, (int)T, FFF, DD);
  mgemm_kernel<1, 0><<<dim3(DD / 128, T / 128), dim3(256), 0, stream>>>(
      hid_bf, Wff2T, nullptr, mlp, (int)T, DD, FFF);

  add_ln_kernel<<<dim3(T), dim3(512), 0, stream>>>(x1, mlp, g3, bt3, out, nullptr);
}